// Round 18
// baseline (174.192 us; speedup 1.0000x reference)
//
#include <hip/hip_runtime.h>
#include <hip/hip_bf16.h>
#include <math.h>

namespace {

typedef __attribute__((ext_vector_type(4))) float f32x4;
typedef __attribute__((ext_vector_type(8))) short s16x8;
typedef __attribute__((ext_vector_type(4))) short s16x4;
typedef unsigned short ushort_t;

constexpr int kB = 2, kT = 1400, kC = 256, kH = 16, kFF = 1024;
constexpr int kBT = kB * kT;
constexpr float kEps = 1e-5f;
constexpr int kSP = 5;               // s-split (5*280 = 1400)
constexpr int kSLen = 280;
constexpr int SBLK = 288;            // 9 chunks of 32
constexpr int KPITCH = 24;           // K row pitch (48 B)
constexpr float kQScale   = 0.25f * 1.4426950408889634f;   // 1/sqrt(D) * log2(e)
constexpr float kAffScale = 0.1f * 1.4426950408889634f;    // 0.1 * log2(e)

__device__ __forceinline__ ushort_t f2bf(float f) {
    unsigned u = __float_as_uint(f);
    u += 0x7fffu + ((u >> 16) & 1u);
    return (ushort_t)(u >> 16);
}
__device__ __forceinline__ float bf2f(ushort_t u) {
    return __uint_as_float(((unsigned)u) << 16);
}
__device__ __forceinline__ unsigned pk2bf(float a, float b) {
    __hip_bfloat162 t = __float22bfloat162_rn(make_float2(a, b));
    union { __hip_bfloat162 h; unsigned u; } cv; cv.h = t;
    return cv.u;
}
__device__ __forceinline__ float fast_exp2(float x) {
    float r;
    asm("v_exp_f32 %0, %1" : "=v"(r) : "v"(x));
    return r;
}

// ---------- weight convert/pack ----------
__global__ __launch_bounds__(256) void convert_kernel(
        const float* __restrict__ in_proj_w, const float* __restrict__ gq_w,
        const float* __restrict__ gk_w, const float* __restrict__ gv_w,
        const float* __restrict__ out_proj_w, const float* __restrict__ go_w,
        const float* __restrict__ ffn_w1, const float* __restrict__ ffn_w2,
        const float* __restrict__ read_w, const float* __restrict__ mem_bank,
        const float* __restrict__ gq_b, const float* __restrict__ gk_b,
        const float* __restrict__ gv_b,
        ushort_t* __restrict__ wdst, float* __restrict__ gqkvb) {
    const int bid = blockIdx.x, tid = threadIdx.x;
    if (bid == 608) {
        gqkvb[tid] = gq_b[tid];
        gqkvb[256 + tid] = gk_b[tid];
        gqkvb[512 + tid] = gv_b[tid];
        return;
    }
    const int u0 = (bid * 256 + tid) * 8;
    if (u0 >= 1114112) {  // mem_bank transpose
        #pragma unroll
        for (int j = 0; j < 8; j++) {
            const int d = u0 - 1114112 + j;
            wdst[1114112 + d] = f2bf(mem_bank[(d & 255) * 256 + (d >> 8)]);
        }
        return;
    }
    const float* src; int off;
    if      (u0 < 196608)  { src = in_proj_w;  off = u0; }
    else if (u0 < 262144)  { src = gq_w;       off = u0 - 196608; }
    else if (u0 < 327680)  { src = gk_w;       off = u0 - 262144; }
    else if (u0 < 393216)  { src = gv_w;       off = u0 - 327680; }
    else if (u0 < 458752)  { src = out_proj_w; off = u0 - 393216; }
    else if (u0 < 524288)  { src = go_w;       off = u0 - 458752; }
    else if (u0 < 786432)  { src = ffn_w1;     off = u0 - 524288; }
    else if (u0 < 1048576) { src = ffn_w2;     off = u0 - 786432; }
    else                   { src = read_w;     off = u0 - 1048576; }
    #pragma unroll
    for (int j = 0; j < 8; j++) wdst[u0 + j] = f2bf(src[off + j]);
}

// ---------- fused (optional LN) + qkv GEMM, 16 complete rows per block ----
// A = LN(xin) (fp32 path) or hin (bf16 path); out = A @ W^T + bias, scattered
// head-major Q(xQScale)/K/V. N = 768, each wave owns 192 cols.
__global__ __launch_bounds__(256) void qkvln_kernel(
        const float* __restrict__ xin, const ushort_t* __restrict__ hin,
        const float* __restrict__ lng, const float* __restrict__ lnb,
        const ushort_t* __restrict__ W, const float* __restrict__ bias,
        ushort_t* __restrict__ outQ, ushort_t* __restrict__ outK,
        ushort_t* __restrict__ outV) {
    __shared__ ushort_t dsA[16 * 256];
    const int tid = threadIdx.x;
    const int lane = tid & 63, wave = tid >> 6;
    const int qi = lane & 15, g = lane >> 4;
    const int m0 = blockIdx.x * 16;

    if (xin) {
        // LN path: thread (r = tid>>4, e = tid&15) owns 16 cols of one row
        const int r = tid >> 4, e = tid & 15;
        const float* xr = xin + (size_t)(m0 + r) * 256 + e * 16;
        const float4 v0 = *(const float4*)&xr[0];
        const float4 v1 = *(const float4*)&xr[4];
        const float4 v2 = *(const float4*)&xr[8];
        const float4 v3 = *(const float4*)&xr[12];
        float s1 = ((v0.x + v0.y) + (v0.z + v0.w)) + ((v1.x + v1.y) + (v1.z + v1.w))
                 + ((v2.x + v2.y) + (v2.z + v2.w)) + ((v3.x + v3.y) + (v3.z + v3.w));
        float s2 = ((v0.x * v0.x + v0.y * v0.y) + (v0.z * v0.z + v0.w * v0.w))
                 + ((v1.x * v1.x + v1.y * v1.y) + (v1.z * v1.z + v1.w * v1.w))
                 + ((v2.x * v2.x + v2.y * v2.y) + (v2.z * v2.z + v2.w * v2.w))
                 + ((v3.x * v3.x + v3.y * v3.y) + (v3.z * v3.z + v3.w * v3.w));
        s1 += __shfl_xor(s1, 1); s2 += __shfl_xor(s2, 1);
        s1 += __shfl_xor(s1, 2); s2 += __shfl_xor(s2, 2);
        s1 += __shfl_xor(s1, 4); s2 += __shfl_xor(s2, 4);
        s1 += __shfl_xor(s1, 8); s2 += __shfl_xor(s2, 8);
        const float mean = s1 * (1.f / 256.f);
        const float rstd = rsqrtf(s2 * (1.f / 256.f) - mean * mean + kEps);
        const int c0 = e * 16;
        const float4 ga = *(const float4*)&lng[c0];
        const float4 gb = *(const float4*)&lng[c0 + 4];
        const float4 gc = *(const float4*)&lng[c0 + 8];
        const float4 gd = *(const float4*)&lng[c0 + 12];
        const float4 ba = *(const float4*)&lnb[c0];
        const float4 bb = *(const float4*)&lnb[c0 + 4];
        const float4 bc = *(const float4*)&lnb[c0 + 8];
        const float4 bd = *(const float4*)&lnb[c0 + 12];
        union { unsigned u4[4]; s16x8 s; } p0, p1;
        p0.u4[0] = pk2bf((v0.x - mean) * rstd * ga.x + ba.x,
                         (v0.y - mean) * rstd * ga.y + ba.y);
        p0.u4[1] = pk2bf((v0.z - mean) * rstd * ga.z + ba.z,
                         (v0.w - mean) * rstd * ga.w + ba.w);
        p0.u4[2] = pk2bf((v1.x - mean) * rstd * gb.x + bb.x,
                         (v1.y - mean) * rstd * gb.y + bb.y);
        p0.u4[3] = pk2bf((v1.z - mean) * rstd * gb.z + bb.z,
                         (v1.w - mean) * rstd * gb.w + bb.w);
        p1.u4[0] = pk2bf((v2.x - mean) * rstd * gc.x + bc.x,
                         (v2.y - mean) * rstd * gc.y + bc.y);
        p1.u4[1] = pk2bf((v2.z - mean) * rstd * gc.z + bc.z,
                         (v2.w - mean) * rstd * gc.w + bc.w);
        p1.u4[2] = pk2bf((v3.x - mean) * rstd * gd.x + bd.x,
                         (v3.y - mean) * rstd * gd.y + bd.y);
        p1.u4[3] = pk2bf((v3.z - mean) * rstd * gd.z + bd.z,
                         (v3.w - mean) * rstd * gd.w + bd.w);
        const int cg0 = e * 2, cg1 = e * 2 + 1;
        *(s16x8*)&dsA[r * 256 + ((cg0 ^ (r & 7)) << 3)] = p0.s;
        *(s16x8*)&dsA[r * 256 + ((cg1 ^ (r & 7)) << 3)] = p1.s;
    } else {
        const int r = tid >> 4, e = tid & 15;
        const ushort_t* hr = hin + (size_t)(m0 + r) * 256 + e * 16;
        #pragma unroll
        for (int i = 0; i < 2; i++) {
            const s16x8 v = *(const s16x8*)&hr[i * 8];
            const int cg = e * 2 + i;
            *(s16x8*)&dsA[r * 256 + ((cg ^ (r & 7)) << 3)] = v;
        }
    }
    __syncthreads();
    f32x4 acc[12] = {};
    const int cbase = wave * 192;
    for (int kt = 0; kt < 8; ++kt) {
        const int cg = kt * 4 + g;
        const s16x8 af = *(const s16x8*)&dsA[qi * 256 + ((cg ^ (qi & 7)) << 3)];
        #pragma unroll
        for (int nn = 0; nn < 12; ++nn) {
            const int wr = cbase + nn * 16 + qi;
            const s16x8 bf = *(const s16x8*)&W[(size_t)wr * 256 + kt * 32 + g * 8];
            acc[nn] = __builtin_amdgcn_mfma_f32_16x16x32_bf16(af, bf, acc[nn], 0, 0, 0);
        }
    }
    #pragma unroll
    for (int nn = 0; nn < 12; ++nn) {
        const int col = cbase + nn * 16 + qi;
        const float bv = bias[col];
        const int hh = (col & 255) >> 4, dd = col & 15;
        #pragma unroll
        for (int r = 0; r < 4; ++r) {
            const int gm = m0 + 4 * g + r;
            const int b = (gm >= kT) ? 1 : 0;
            const int ss = gm - b * kT;
            const size_t hoff = (((size_t)(b * 16 + hh)) * kT + ss) * 16 + dd;
            const float v = acc[nn][r] + bv;
            if (col < 256)      outQ[hoff] = f2bf(v * kQScale);
            else if (col < 512) outK[hoff] = f2bf(v);
            else                outV[hoff] = f2bf(v);
        }
    }
}

// ---------- fused FFN: out = x3 + gelu(h @ W1^T + b1) @ W2^T + b2 ----------
// 16 complete rows per block; ff1 lives in LDS (32 KB), never touches global.
__global__ __launch_bounds__(256) void ffn_kernel(
        const ushort_t* __restrict__ hin, const ushort_t* __restrict__ wF1,
        const float* __restrict__ b1, const ushort_t* __restrict__ wF2,
        const float* __restrict__ b2, const float* __restrict__ x3,
        float* __restrict__ out) {
    __shared__ ushort_t dsH[16 * 256];    //  8 KB
    __shared__ ushort_t dsF[16 * 1024];   // 32 KB
    const int tid = threadIdx.x;
    const int lane = tid & 63, wave = tid >> 6;
    const int qi = lane & 15, g = lane >> 4;
    const int wn = wave * 64;
    const int m0 = blockIdx.x * 16;

    // stage h rows (bf16), swizzled
    {
        const int r = tid >> 4, e = tid & 15;
        const ushort_t* hr = hin + (size_t)(m0 + r) * 256 + e * 16;
        #pragma unroll
        for (int i = 0; i < 2; i++) {
            const s16x8 v = *(const s16x8*)&hr[i * 8];
            const int cg = e * 2 + i;
            *(s16x8*)&dsH[r * 256 + ((cg ^ (r & 7)) << 3)] = v;
        }
    }
    __syncthreads();
    // phase 1: ff1 = gelu(h @ W1^T + b1), in 4 column chunks of 256
    #pragma unroll
    for (int cc = 0; cc < 4; ++cc) {
        f32x4 acc[4] = {};
        for (int kt = 0; kt < 8; ++kt) {
            const int cg = kt * 4 + g;
            const s16x8 af = *(const s16x8*)&dsH[qi * 256 + ((cg ^ (qi & 7)) << 3)];
            #pragma unroll
            for (int nn = 0; nn < 4; ++nn) {
                const int wr = cc * 256 + wn + nn * 16 + qi;
                const s16x8 bf = *(const s16x8*)&wF1[(size_t)wr * 256 + kt * 32 + g * 8];
                acc[nn] = __builtin_amdgcn_mfma_f32_16x16x32_bf16(af, bf, acc[nn], 0, 0, 0);
            }
        }
        #pragma unroll
        for (int nn = 0; nn < 4; ++nn) {
            const int col = cc * 256 + wn + nn * 16 + qi;
            const float bv = b1[col];
            #pragma unroll
            for (int r = 0; r < 4; ++r) {
                const int row = 4 * g + r;
                float v = acc[nn][r] + bv;
                v = 0.5f * v * (1.f + erff(v * 0.70710678f));
                const int cg = col >> 3, e = col & 7;
                dsF[row * 1024 + ((cg ^ (row & 7)) << 3) + e] = f2bf(v);
            }
        }
    }
    __syncthreads();
    // phase 2: out = x3 + ff1 @ W2^T + b2  (K = 1024 from LDS)
    f32x4 acc2[4] = {};
    for (int kt = 0; kt < 32; ++kt) {
        const int cg = kt * 4 + g;
        const s16x8 af = *(const s16x8*)&dsF[qi * 1024 + ((cg ^ (qi & 7)) << 3)];
        #pragma unroll
        for (int nn = 0; nn < 4; ++nn) {
            const int wr = wn + nn * 16 + qi;
            const s16x8 bf = *(const s16x8*)&wF2[(size_t)wr * 1024 + kt * 32 + g * 8];
            acc2[nn] = __builtin_amdgcn_mfma_f32_16x16x32_bf16(af, bf, acc2[nn], 0, 0, 0);
        }
    }
    #pragma unroll
    for (int nn = 0; nn < 4; ++nn) {
        const int col = wn + nn * 16 + qi;
        const float bv = b2[col];
        #pragma unroll
        for (int r = 0; r < 4; ++r) {
            const int row = 4 * g + r;
            const size_t idx = (size_t)(m0 + row) * 256 + col;
            out[idx] = acc2[nn][r] + bv + x3[idx];
        }
    }
}

// ---------- fused combine + proj GEMM + residual (+ optional LN) --------
__global__ __launch_bounds__(256) void gemmcomb_kernel(
        const ushort_t* __restrict__ o_part, const float* __restrict__ l_part,
        const ushort_t* __restrict__ W, const float* __restrict__ bias,
        const float* __restrict__ res,
        const float* __restrict__ lng, const float* __restrict__ lnb,
        float* __restrict__ outf, ushort_t* __restrict__ outln) {
    __shared__ ushort_t dsA[16 * 256];
    __shared__ float ws1[4][16], ws2[4][16];
    const int tid = threadIdx.x;
    const int lane = tid & 63, wave = tid >> 6;
    const int qi = lane & 15, g = lane >> 4;
    const int wn = wave * 64;
    const int m0 = blockIdx.x * 16;

    {
        const int h = tid >> 4, r = tid & 15;
        const int gm = m0 + r;
        const int b = (gm >= kT) ? 1 : 0;
        const int t = gm - b * kT;
        float f[16] = {};
        float l = 0.f;
        #pragma unroll
        for (int p = 0; p < kSP; ++p) {
            const size_t sl_ = (size_t)((b * kSP + p) * 16 + h);
            l += l_part[sl_ * kT + t];
            const s16x8 v0 = *(const s16x8*)&o_part[(sl_ * kT + t) * 16];
            const s16x8 v1 = *(const s16x8*)&o_part[(sl_ * kT + t) * 16 + 8];
            #pragma unroll
            for (int j = 0; j < 8; j++) {
                f[j]     += bf2f((ushort_t)v0[j]);
                f[8 + j] += bf2f((ushort_t)v1[j]);
            }
        }
        const float li = 1.f / l;
        union { unsigned u4[4]; s16x8 s; } p0, p1;
        p0.u4[0] = pk2bf(f[0] * li, f[1] * li);
        p0.u4[1] = pk2bf(f[2] * li, f[3] * li);
        p0.u4[2] = pk2bf(f[4] * li, f[5] * li);
        p0.u4[3] = pk2bf(f[6] * li, f[7] * li);
        p1.u4[0] = pk2bf(f[8] * li, f[9] * li);
        p1.u4[1] = pk2bf(f[10] * li, f[11] * li);
        p1.u4[2] = pk2bf(f[12] * li, f[13] * li);
        p1.u4[3] = pk2bf(f[14] * li, f[15] * li);
        const int cg0 = h * 2, cg1 = h * 2 + 1;
        *(s16x8*)&dsA[r * 256 + ((cg0 ^ (r & 7)) << 3)] = p0.s;
        *(s16x8*)&dsA[r * 256 + ((cg1 ^ (r & 7)) << 3)] = p1.s;
    }
    __syncthreads();
    f32x4 acc[4] = {};
    for (int kt = 0; kt < 8; ++kt) {
        const int cg = kt * 4 + g;
        const s16x8 af = *(const s16x8*)&dsA[qi * 256 + ((cg ^ (qi & 7)) << 3)];
        #pragma unroll
        for (int nn = 0; nn < 4; ++nn) {
            const int wr = wn + nn * 16 + qi;
            const s16x8 bf = *(const s16x8*)&W[(size_t)wr * 256 + kt * 32 + g * 8];
            acc[nn] = __builtin_amdgcn_mfma_f32_16x16x32_bf16(af, bf, acc[nn], 0, 0, 0);
        }
    }
    float v[4][4];
    float s1[4] = {0.f, 0.f, 0.f, 0.f}, s2[4] = {0.f, 0.f, 0.f, 0.f};
    #pragma unroll
    for (int nn = 0; nn < 4; ++nn) {
        #pragma unroll
        for (int r = 0; r < 4; ++r) {
            const int row = 4 * g + r, col = wn + nn * 16 + qi;
            const size_t idx = (size_t)(m0 + row) * 256 + col;
            const float t = acc[nn][r] + bias[col] + res[idx];
            outf[idx] = t;
            v[nn][r] = t;
            s1[r] += t; s2[r] += t * t;
        }
    }
    if (outln) {
        #pragma unroll
        for (int r = 0; r < 4; ++r) {
            s1[r] += __shfl_xor(s1[r], 1); s2[r] += __shfl_xor(s2[r], 1);
            s1[r] += __shfl_xor(s1[r], 2); s2[r] += __shfl_xor(s2[r], 2);
            s1[r] += __shfl_xor(s1[r], 4); s2[r] += __shfl_xor(s2[r], 4);
            s1[r] += __shfl_xor(s1[r], 8); s2[r] += __shfl_xor(s2[r], 8);
        }
        if (qi == 0) {
            #pragma unroll
            for (int r = 0; r < 4; ++r) { ws1[wave][4 * g + r] = s1[r]; ws2[wave][4 * g + r] = s2[r]; }
        }
        __syncthreads();
        #pragma unroll
        for (int r = 0; r < 4; ++r) {
            const int row = 4 * g + r;
            const float S1 = ws1[0][row] + ws1[1][row] + ws1[2][row] + ws1[3][row];
            const float S2 = ws2[0][row] + ws2[1][row] + ws2[2][row] + ws2[3][row];
            const float mean = S1 * (1.f / 256.f);
            const float rstd = rsqrtf(S2 * (1.f / 256.f) - mean * mean + kEps);
            #pragma unroll
            for (int nn = 0; nn < 4; ++nn) {
                const int col = wn + nn * 16 + qi;
                outln[(size_t)(m0 + row) * 256 + col] =
                    f2bf((v[nn][r] - mean) * rstd * lng[col] + lnb[col]);
            }
        }
    }
}

// ---------- fused memory-bank read + LN3 ----------
__global__ __launch_bounds__(256) void memread_kernel(
        const float* __restrict__ x2, const ushort_t* __restrict__ wRead,
        const float* __restrict__ read_b, const ushort_t* __restrict__ wMemT,
        const float* __restrict__ lng, const float* __restrict__ lnb,
        float* __restrict__ xout, ushort_t* __restrict__ outln) {
    __shared__ ushort_t dsP[16 * 256];
    __shared__ float lsum[4][16];
    __shared__ float lt[16];
    __shared__ float ws1[4][16], ws2[4][16];
    const int tid = threadIdx.x;
    const int lane = tid & 63, wave = tid >> 6;
    const int qi = lane & 15, g = lane >> 4;
    const int wn = wave * 64;
    const int m0 = blockIdx.x * 16;

    {
        const int r = tid >> 4, e = tid & 15;
        const float* xr = x2 + (size_t)(m0 + r) * 256 + e * 16;
        #pragma unroll
        for (int i = 0; i < 2; i++) {
            const float4 va = *(const float4*)&xr[i * 8];
            const float4 vb = *(const float4*)&xr[i * 8 + 4];
            union { unsigned u4[4]; s16x8 s; } pu;
            pu.u4[0] = pk2bf(va.x, va.y);
            pu.u4[1] = pk2bf(va.z, va.w);
            pu.u4[2] = pk2bf(vb.x, vb.y);
            pu.u4[3] = pk2bf(vb.z, vb.w);
            const int cg = e * 2 + i;
            *(s16x8*)&dsP[r * 256 + ((cg ^ (r & 7)) << 3)] = pu.s;
        }
    }
    __syncthreads();
    f32x4 acc[4] = {};
    for (int kt = 0; kt < 8; ++kt) {
        const int cg = kt * 4 + g;
        const s16x8 af = *(const s16x8*)&dsP[qi * 256 + ((cg ^ (qi & 7)) << 3)];
        #pragma unroll
        for (int nn = 0; nn < 4; ++nn) {
            const int wr = wn + nn * 16 + qi;
            const s16x8 bf = *(const s16x8*)&wRead[(size_t)wr * 256 + kt * 32 + g * 8];
            acc[nn] = __builtin_amdgcn_mfma_f32_16x16x32_bf16(af, bf, acc[nn], 0, 0, 0);
        }
    }
    float p[4][4];
    float rs[4] = {0.f, 0.f, 0.f, 0.f};
    #pragma unroll
    for (int nn = 0; nn < 4; ++nn) {
        const float bb = read_b[wn + nn * 16 + qi];
        #pragma unroll
        for (int r = 0; r < 4; ++r) {
            p[nn][r] = __expf(acc[nn][r] + bb);
            rs[r] += p[nn][r];
        }
    }
    #pragma unroll
    for (int r = 0; r < 4; ++r) {
        rs[r] += __shfl_xor(rs[r], 1);
        rs[r] += __shfl_xor(rs[r], 2);
        rs[r] += __shfl_xor(rs[r], 4);
        rs[r] += __shfl_xor(rs[r], 8);
    }
    __syncthreads();
    if (qi == 0) {
        #pragma unroll
        for (int r = 0; r < 4; ++r) lsum[wave][4 * g + r] = rs[r];
    }
    #pragma unroll
    for (int nn = 0; nn < 4; ++nn) {
        #pragma unroll
        for (int r = 0; r < 4; ++r) {
            const int row = 4 * g + r, col = wn + nn * 16 + qi;
            const int cg = col >> 3, e = col & 7;
            dsP[row * 256 + ((cg ^ (row & 7)) << 3) + e] = f2bf(p[nn][r]);
        }
    }
    __syncthreads();
    if (tid < 16)
        lt[tid] = 1.f / (lsum[0][tid] + lsum[1][tid] + lsum[2][tid] + lsum[3][tid]);
    __syncthreads();
    f32x4 acc2[4] = {};
    for (int kt = 0; kt < 8; ++kt) {
        const int cg = kt * 4 + g;
        const s16x8 af = *(const s16x8*)&dsP[qi * 256 + ((cg ^ (qi & 7)) << 3)];
        #pragma unroll
        for (int nn = 0; nn < 4; ++nn) {
            const int wr = wn + nn * 16 + qi;
            const s16x8 bf = *(const s16x8*)&wMemT[(size_t)wr * 256 + kt * 32 + g * 8];
            acc2[nn] = __builtin_amdgcn_mfma_f32_16x16x32_bf16(af, bf, acc2[nn], 0, 0, 0);
        }
    }
    float xo[4][4];
    float s1[4] = {0.f, 0.f, 0.f, 0.f}, s2[4] = {0.f, 0.f, 0.f, 0.f};
    #pragma unroll
    for (int nn = 0; nn < 4; ++nn) {
        #pragma unroll
        for (int r = 0; r < 4; ++r) {
            const int row = 4 * g + r;
            const size_t idx = (size_t)(m0 + row) * 256 + wn + nn * 16 + qi;
            const float t = acc2[nn][r] * lt[row] + x2[idx];
            xout[idx] = t;
            xo[nn][r] = t;
            s1[r] += t; s2[r] += t * t;
        }
    }
    #pragma unroll
    for (int r = 0; r < 4; ++r) {
        s1[r] += __shfl_xor(s1[r], 1); s2[r] += __shfl_xor(s2[r], 1);
        s1[r] += __shfl_xor(s1[r], 2); s2[r] += __shfl_xor(s2[r], 2);
        s1[r] += __shfl_xor(s1[r], 4); s2[r] += __shfl_xor(s2[r], 4);
        s1[r] += __shfl_xor(s1[r], 8); s2[r] += __shfl_xor(s2[r], 8);
    }
    if (qi == 0) {
        #pragma unroll
        for (int r = 0; r < 4; ++r) { ws1[wave][4 * g + r] = s1[r]; ws2[wave][4 * g + r] = s2[r]; }
    }
    __syncthreads();
    #pragma unroll
    for (int r = 0; r < 4; ++r) {
        const int row = 4 * g + r;
        const float S1 = ws1[0][row] + ws1[1][row] + ws1[2][row] + ws1[3][row];
        const float S2 = ws2[0][row] + ws2[1][row] + ws2[2][row] + ws2[3][row];
        const float mean = S1 * (1.f / 256.f);
        const float rstd = rsqrtf(S2 * (1.f / 256.f) - mean * mean + kEps);
        #pragma unroll
        for (int nn = 0; nn < 4; ++nn) {
            const int col = wn + nn * 16 + qi;
            outln[(size_t)(m0 + row) * 256 + col] =
                f2bf((xo[nn][r] - mean) * rstd * lng[col] + lnb[col]);
        }
    }
}

// ---------- flash MFMA attention: kSP=5, QBLK=128, prefetched tr_read PV --
template <bool kAff>
__global__ __launch_bounds__(512) void attn_mfma_kernel(
        const ushort_t* __restrict__ q, const ushort_t* __restrict__ kbuf,
        const ushort_t* __restrict__ vbuf, ushort_t* __restrict__ o_part,
        float* __restrict__ l_part,
        const float* __restrict__ affinity, const int* __restrict__ did) {
    __shared__ ushort_t ldsK[SBLK * KPITCH];   // [s][d]  13824 B
    __shared__ ushort_t ldsV[SBLK * 16];       // [s][d]   9216 B
    const int tid  = threadIdx.x;
    const int bid  = blockIdx.x;
    const int w    = (bid & 7) * 220 + (bid >> 3);
    const int slice = w / 11;
    const int ttile = w - slice * 11;
    const int h    = slice & 15;
    const int z    = slice >> 4;
    const int b    = (z >= 5) ? 1 : 0;
    const int sp   = z - b * 5;
    const int t0   = ttile * 128;
    const int s0   = sp * kSLen;
    const int lane = tid & 63;
    const int wave = tid >> 6;
    const int g    = lane >> 4;
    const int qi   = lane & 15;

    const int tq  = t0 + wave * 16 + qi;
    const int tqc = min(tq, kT - 1);
    const ushort_t* qhb = q + (size_t)(b * 16 + h) * kT * 16;
    s16x8 qb = {0, 0, 0, 0, 0, 0, 0, 0};
    if (g < 2) qb = *(const s16x8*)&qhb[(size_t)tqc * 16 + g * 8];
    const float* ar = nullptr;
    if (kAff) ar = affinity + (size_t)did[b * kT + tqc] * kT;

    const ushort_t* kb  = kbuf + (size_t)(b * 16 + h) * kT * 16;
    const ushort_t* vbp = vbuf + (size_t)(b * 16 + h) * kT * 16;
    for (int i = tid; i < SBLK * 2; i += 512) {
        const int sl = i >> 1, hf = i & 1;
        const int sg = min(s0 + sl, kT - 1);
        *(s16x8*)&ldsK[sl * KPITCH + hf * 8] =
            *(const s16x8*)&kb[(size_t)sg * 16 + hf * 8];
        *(s16x8*)&ldsV[sl * 16 + hf * 8] =
            *(const s16x8*)&vbp[(size_t)sg * 16 + hf * 8];
    }
    __syncthreads();

    f32x4 acc = {0.f, 0.f, 0.f, 0.f};
    float lrun = 0.f;
    const unsigned vaddr = (unsigned)(size_t)(&ldsV[0]) + lane * 8;
    s16x4 va0, va1;
    asm volatile("ds_read_b64_tr_b16 %0, %2\n\t"
                 "ds_read_b64_tr_b16 %1, %2 offset:512"
                 : "=&v"(va0), "=&v"(va1) : "v"(vaddr));

    #pragma unroll
    for (int c = 0; c < SBLK / 32; ++c) {
        const int sl0 = c * 32;
        const bool tail = (c == 8);
        const s16x8 ka0 = *(const s16x8*)&ldsK[(sl0 + qi) * KPITCH + (g & 1) * 8];
        const s16x8 ka1 = *(const s16x8*)&ldsK[(sl0 + 16 + qi) * KPITCH + (g & 1) * 8];
        const f32x4 z4 = {0.f, 0.f, 0.f, 0.f};
        f32x4 d0 = __builtin_amdgcn_mfma_f32_16x16x32_bf16(ka0, qb, z4, 0, 0, 0);
        f32x4 d1 = __builtin_amdgcn_mfma_f32_16x16x32_bf16(ka1, qb, z4, 0, 0, 0);
        float sv[8];
        #pragma unroll
        for (int r = 0; r < 4; r++) { sv[r] = d0[r]; sv[4 + r] = d1[r]; }
        if (kAff) {
            if (!tail) {
                const float4 a0 = *(const float4*)&ar[s0 + sl0 + 4 * g];
                const float4 a1 = *(const float4*)&ar[s0 + sl0 + 16 + 4 * g];
                sv[0] += kAffScale * a0.x; sv[1] += kAffScale * a0.y;
                sv[2] += kAffScale * a0.z; sv[3] += kAffScale * a0.w;
                sv[4] += kAffScale * a1.x; sv[5] += kAffScale * a1.y;
                sv[6] += kAffScale * a1.z; sv[7] += kAffScale * a1.w;
            } else {
                #pragma unroll
                for (int jj = 0; jj < 8; jj++) {
                    const int s_ = s0 + sl0 + 16 * (jj >> 2) + 4 * g + (jj & 3);
                    sv[jj] += kAffScale * ar[min(s_, kT - 1)];
                }
            }
        }
        float pv[8];
        #pragma unroll
        for (int jj = 0; jj < 8; jj++) pv[jj] = fast_exp2(sv[jj]);
        if (tail && g >= 2) { pv[4] = 0.f; pv[5] = 0.f; pv[6] = 0.f; pv[7] = 0.f; }
        lrun += ((pv[0] + pv[1]) + (pv[2] + pv[3])) + ((pv[4] + pv[5]) + (pv[6] + pv[7]));
        union { unsigned u[4]; s16x8 s; } pu;
        pu.u[0] = pk2bf(pv[0], pv[1]);
        pu.u[1] = pk2bf(pv[2], pv[3]);
        pu.u[2] = pk2bf(pv[4], pv[5]);
        pu.u[3] = pk2bf(pv[6], pv[7]);
        asm volatile("s_waitcnt lgkmcnt(0)" ::: "memory");
        __builtin_amdgcn_sched_barrier(0);   // rule 18
        s16x8 af;
        #pragma unroll
        for (int j = 0; j < 4; j++) { af[j] = va0[j]; af[4 + j] = va1[j]; }
        acc = __builtin_amdgcn_mfma_f32_16x16x32_bf16(af, pu.s, acc, 0, 0, 0);
        if (c < SBLK / 32 - 1) {
            asm volatile("ds_read_b64_tr_b16 %0, %2\n\t"
                         "ds_read_b64_tr_b16 %1, %2 offset:512"
                         : "=&v"(va0), "=&v"(va1) : "v"(vaddr + (sl0 + 32) * 32));
        }
    }
    lrun += __shfl_xor(lrun, 16);
    lrun += __shfl_xor(lrun, 32);
    const int slice_id = (b * kSP + sp) * 16 + h;
    if (lane < 16 && tq < kT)
        l_part[(size_t)slice_id * kT + tq] = lrun;
    ushort_t* ob = o_part + (size_t)slice_id * kT * 16;
    s16x4 ov;
    #pragma unroll
    for (int r = 0; r < 4; r++) ov[r] = (short)f2bf(acc[r]);
    if (tq < kT) *(s16x4*)&ob[(size_t)tq * 16 + 4 * g] = ov;
}

}  // namespace

extern "C" void kernel_launch(void* const* d_in, const int* in_sizes, int n_in,
                              void* d_out, int out_size, void* d_ws, size_t ws_size,
                              hipStream_t stream) {
    const float* x          = (const float*)d_in[0];
    const int*   did        = (const int*)d_in[1];
    const float* in_proj_w  = (const float*)d_in[2];
    const float* in_proj_b  = (const float*)d_in[3];
    const float* out_proj_w = (const float*)d_in[4];
    const float* out_proj_b = (const float*)d_in[5];
    const float* ln1_g = (const float*)d_in[6];
    const float* ln1_b = (const float*)d_in[7];
    const float* ln2_g = (const float*)d_in[8];
    const float* ln2_b = (const float*)d_in[9];
    const float* ln3_g = (const float*)d_in[10];
    const float* ln3_b = (const float*)d_in[11];
    const float* gq_w = (const float*)d_in[12];
    const float* gq_b = (const float*)d_in[13];
    const float* gk_w = (const float*)d_in[14];
    const float* gk_b = (const float*)d_in[15];
    const float* gv_w = (const float*)d_in[16];
    const float* gv_b = (const float*)d_in[17];
    const float* go_w = (const float*)d_in[18];
    const float* go_b = (const float*)d_in[19];
    const float* affinity = (const float*)d_in[20];
    const float* mem_bank = (const float*)d_in[21];
    const float* read_w   = (const float*)d_in[22];
    const float* read_b   = (const float*)d_in[23];
    const float* ffn_w1 = (const float*)d_in[24];
    const float* ffn_b1 = (const float*)d_in[25];
    const float* ffn_w2 = (const float*)d_in[26];
    const float* ffn_b2 = (const float*)d_in[27];

    // ---- workspace layout (byte offsets; lifetimes hand-verified) ----
    char* wsb = (char*)d_ws;
    ushort_t* o_part  = (ushort_t*)(wsb + 0);          // [160][kT][16] bf16
    float*    l_part  = (float*)(wsb + 7168000);       // [160][kT] fp32
    float*    bufD    = (float*)(wsb + 13798400);      // fp32 x2/x3
    ushort_t* bufA16  = (ushort_t*)(wsb + 16665600);   // bf16 LN out
    float*    bufD2   = (float*)(wsb + 18099200);      // fp32 x1
    ushort_t* bufQ16  = (ushort_t*)(wsb + 20966400);   // [B][H][T][16] (xQScale)
    ushort_t* bufK16  = (ushort_t*)(wsb + 22400000);   // [B][H][T][16]
    ushort_t* bufV16  = (ushort_t*)(wsb + 23833600);   // [B][H][T][16]
    ushort_t* wdst    = (ushort_t*)(wsb + 26700800);   // bf16 weights
    float*    gqkvb   = (float*)(wsb + 29191168);      // [768]

    const ushort_t* wQKV1 = wdst;
    const ushort_t* wG    = wdst + 196608;
    const ushort_t* wO    = wdst + 393216;
    const ushort_t* wGO   = wdst + 458752;
    const ushort_t* wF1   = wdst + 524288;
    const ushort_t* wF2   = wdst + 786432;
    const ushort_t* wRead = wdst + 1048576;
    const ushort_t* wMemT = wdst + 1114112;

    const dim3 blk(256);
    const dim3 g_row(kBT / 16);            // 175
    const dim3 g_at(11 * kH * kB * kSP);   // 1760 = 8 * 220

    convert_kernel<<<609, blk, 0, stream>>>(in_proj_w, gq_w, gk_w, gv_w, out_proj_w,
                                            go_w, ffn_w1, ffn_w2, read_w, mem_bank,
                                            gq_b, gk_b, gv_b, wdst, gqkvb);
    // 1+2. qkv = LN1(x) @ in_proj^T + b -> head-major Q(xQScale)/K/V
    qkvln_kernel<<<g_row, blk, 0, stream>>>(x, nullptr, ln1_g, ln1_b,
                                            wQKV1, in_proj_b,
                                            bufQ16, bufK16, bufV16);
    // 3. MHA partials
    attn_mfma_kernel<false><<<g_at, dim3(512), 0, stream>>>(bufQ16, bufK16, bufV16,
                                                            o_part, l_part,
                                                            nullptr, nullptr);
    // 4+5. x1 = x + combine(o) @ out_proj^T + b (fp32) + LN2(x1) bf16, fused
    gemmcomb_kernel<<<g_row, blk, 0, stream>>>(o_part, l_part, wO, out_proj_b,
                                               x, ln2_g, ln2_b, bufD2, bufA16);
    // 6. graph qkv (bf16 direct path)
    qkvln_kernel<<<g_row, blk, 0, stream>>>(nullptr, bufA16, nullptr, nullptr,
                                            wG, gqkvb,
                                            bufQ16, bufK16, bufV16);
    // 7. graph attention partials
    attn_mfma_kernel<true><<<g_at, dim3(512), 0, stream>>>(bufQ16, bufK16, bufV16,
                                                           o_part, l_part,
                                                           affinity, did);
    // 8. x2 = x1 + combine(o2) @ go^T + b -> bufD fp32 (no LN)
    gemmcomb_kernel<<<g_row, blk, 0, stream>>>(o_part, l_part, wGO, go_b,
                                               bufD2, nullptr, nullptr,
                                               bufD, nullptr);
    // 9+10. x3 = x2 + softmax(x2@read_w^T+rb) @ mem_bank (in place) + LN3 fused
    memread_kernel<<<g_row, blk, 0, stream>>>(bufD, wRead, read_b, wMemT,
                                              ln3_g, ln3_b, bufD, bufA16);
    // 11+12. out = x3 + gelu(LN3 @ w1^T + b1) @ w2^T + b2   (ff1 in LDS)
    ffn_kernel<<<g_row, blk, 0, stream>>>(bufA16, wF1, ffn_b1, wF2, ffn_b2,
                                          bufD, (float*)d_out);
}

// Round 19
// 155.076 us; speedup vs baseline: 1.1233x; 1.1233x over previous
//
#include <hip/hip_runtime.h>
#include <hip/hip_bf16.h>
#include <math.h>

namespace {

typedef __attribute__((ext_vector_type(4))) float f32x4;
typedef __attribute__((ext_vector_type(8))) short s16x8;
typedef __attribute__((ext_vector_type(4))) short s16x4;
typedef unsigned short ushort_t;

constexpr int kB = 2, kT = 1400, kC = 256, kH = 16, kFF = 1024;
constexpr int kBT = kB * kT;
constexpr float kEps = 1e-5f;
constexpr int kSP = 5;               // s-split (5*280 = 1400)
constexpr int kSLen = 280;
constexpr int SBLK = 288;            // 9 chunks of 32
constexpr int KPITCH = 24;           // K row pitch (48 B)
constexpr float kQScale   = 0.25f * 1.4426950408889634f;   // 1/sqrt(D) * log2(e)
constexpr float kAffScale = 0.1f * 1.4426950408889634f;    // 0.1 * log2(e)

__device__ __forceinline__ ushort_t f2bf(float f) {
    unsigned u = __float_as_uint(f);
    u += 0x7fffu + ((u >> 16) & 1u);
    return (ushort_t)(u >> 16);
}
__device__ __forceinline__ float bf2f(ushort_t u) {
    return __uint_as_float(((unsigned)u) << 16);
}
__device__ __forceinline__ unsigned pk2bf(float a, float b) {
    __hip_bfloat162 t = __float22bfloat162_rn(make_float2(a, b));
    union { __hip_bfloat162 h; unsigned u; } cv; cv.h = t;
    return cv.u;
}
__device__ __forceinline__ float fast_exp2(float x) {
    float r;
    asm("v_exp_f32 %0, %1" : "=v"(r) : "v"(x));
    return r;
}

// ---------- weight convert/pack ----------
__global__ __launch_bounds__(256) void convert_kernel(
        const float* __restrict__ in_proj_w, const float* __restrict__ gq_w,
        const float* __restrict__ gk_w, const float* __restrict__ gv_w,
        const float* __restrict__ out_proj_w, const float* __restrict__ go_w,
        const float* __restrict__ ffn_w1, const float* __restrict__ ffn_w2,
        const float* __restrict__ read_w, const float* __restrict__ mem_bank,
        const float* __restrict__ gq_b, const float* __restrict__ gk_b,
        const float* __restrict__ gv_b,
        ushort_t* __restrict__ wdst, float* __restrict__ gqkvb) {
    const int bid = blockIdx.x, tid = threadIdx.x;
    if (bid == 608) {
        gqkvb[tid] = gq_b[tid];
        gqkvb[256 + tid] = gk_b[tid];
        gqkvb[512 + tid] = gv_b[tid];
        return;
    }
    const int u0 = (bid * 256 + tid) * 8;
    if (u0 >= 1114112) {  // mem_bank transpose
        #pragma unroll
        for (int j = 0; j < 8; j++) {
            const int d = u0 - 1114112 + j;
            wdst[1114112 + d] = f2bf(mem_bank[(d & 255) * 256 + (d >> 8)]);
        }
        return;
    }
    const float* src; int off;
    if      (u0 < 196608)  { src = in_proj_w;  off = u0; }
    else if (u0 < 262144)  { src = gq_w;       off = u0 - 196608; }
    else if (u0 < 327680)  { src = gk_w;       off = u0 - 262144; }
    else if (u0 < 393216)  { src = gv_w;       off = u0 - 327680; }
    else if (u0 < 458752)  { src = out_proj_w; off = u0 - 393216; }
    else if (u0 < 524288)  { src = go_w;       off = u0 - 458752; }
    else if (u0 < 786432)  { src = ffn_w1;     off = u0 - 524288; }
    else if (u0 < 1048576) { src = ffn_w2;     off = u0 - 786432; }
    else                   { src = read_w;     off = u0 - 1048576; }
    #pragma unroll
    for (int j = 0; j < 8; j++) wdst[u0 + j] = f2bf(src[off + j]);
}

// ---------- bf16 MFMA GEMM: out[m,n] = A[M,K] @ W[N,K]^T + bias ----------
__global__ __launch_bounds__(256) void gemm16_kernel(
        const ushort_t* __restrict__ A, const ushort_t* __restrict__ W,
        const float* __restrict__ bias, const float* __restrict__ res,
        float* __restrict__ outf, ushort_t* __restrict__ outb,
        int M, int N, int K, int ldo, int act) {
    __shared__ ushort_t dsA[64 * 64];
    __shared__ ushort_t dsW[64 * 64];
    const int tid = threadIdx.x;
    const int lane = tid & 63, wave = tid >> 6;
    const int qi = lane & 15, g = lane >> 4;
    const int wm = (wave >> 1) * 32, wn = (wave & 1) * 32;
    const int m0 = blockIdx.x * 64, n0 = blockIdx.y * 64;

    f32x4 acc[2][2] = {};
    for (int kt = 0; kt < K; kt += 64) {
        __syncthreads();
        #pragma unroll
        for (int j = 0; j < 2; ++j) {
            const int u = tid + j * 256;          // 0..511
            const int row = u >> 3, c = u & 7;
            const int cs = c ^ (row & 7);
            const int gmA = min(m0 + row, M - 1);
            *(s16x8*)&dsA[row * 64 + cs * 8] =
                *(const s16x8*)&A[(size_t)gmA * K + kt + c * 8];
            *(s16x8*)&dsW[row * 64 + cs * 8] =
                *(const s16x8*)&W[(size_t)(n0 + row) * K + kt + c * 8];
        }
        __syncthreads();
        #pragma unroll
        for (int kk = 0; kk < 2; ++kk) {
            s16x8 af[2], bf[2];
            #pragma unroll
            for (int f = 0; f < 2; ++f) {
                const int r = wm + f * 16 + qi;
                af[f] = *(const s16x8*)&dsA[r * 64 + (((kk * 4 + g) ^ (r & 7)) * 8)];
            }
            #pragma unroll
            for (int nn = 0; nn < 2; ++nn) {
                const int r = wn + nn * 16 + qi;
                bf[nn] = *(const s16x8*)&dsW[r * 64 + (((kk * 4 + g) ^ (r & 7)) * 8)];
            }
            #pragma unroll
            for (int f = 0; f < 2; ++f)
                #pragma unroll
                for (int nn = 0; nn < 2; ++nn)
                    acc[f][nn] = __builtin_amdgcn_mfma_f32_16x16x32_bf16(
                        af[f], bf[nn], acc[f][nn], 0, 0, 0);
        }
    }
    #pragma unroll
    for (int f = 0; f < 2; ++f) {
        #pragma unroll
        for (int r = 0; r < 4; ++r) {
            const int gm = m0 + wm + f * 16 + g * 4 + r;
            if (gm >= M) continue;
            #pragma unroll
            for (int nn = 0; nn < 2; ++nn) {
                const int gn = n0 + wn + nn * 16 + qi;
                float v = acc[f][nn][r];
                if (bias) v += bias[gn];
                if (act == 1) v = 0.5f * v * (1.f + erff(v * 0.70710678f));
                if (res) v += res[(size_t)gm * ldo + gn];
                if (outf) outf[(size_t)gm * ldo + gn] = v;
                if (outb) outb[(size_t)gm * ldo + gn] = f2bf(v);
            }
        }
    }
}

// ---------- fused (optional LN) + qkv GEMM, 16 complete rows per block ----
__global__ __launch_bounds__(256) void qkvln_kernel(
        const float* __restrict__ xin, const ushort_t* __restrict__ hin,
        const float* __restrict__ lng, const float* __restrict__ lnb,
        const ushort_t* __restrict__ W, const float* __restrict__ bias,
        ushort_t* __restrict__ outQ, ushort_t* __restrict__ outK,
        ushort_t* __restrict__ outV) {
    __shared__ ushort_t dsA[16 * 256];
    const int tid = threadIdx.x;
    const int lane = tid & 63, wave = tid >> 6;
    const int qi = lane & 15, g = lane >> 4;
    const int m0 = blockIdx.x * 16;

    if (xin) {
        const int r = tid >> 4, e = tid & 15;
        const float* xr = xin + (size_t)(m0 + r) * 256 + e * 16;
        const float4 v0 = *(const float4*)&xr[0];
        const float4 v1 = *(const float4*)&xr[4];
        const float4 v2 = *(const float4*)&xr[8];
        const float4 v3 = *(const float4*)&xr[12];
        float s1 = ((v0.x + v0.y) + (v0.z + v0.w)) + ((v1.x + v1.y) + (v1.z + v1.w))
                 + ((v2.x + v2.y) + (v2.z + v2.w)) + ((v3.x + v3.y) + (v3.z + v3.w));
        float s2 = ((v0.x * v0.x + v0.y * v0.y) + (v0.z * v0.z + v0.w * v0.w))
                 + ((v1.x * v1.x + v1.y * v1.y) + (v1.z * v1.z + v1.w * v1.w))
                 + ((v2.x * v2.x + v2.y * v2.y) + (v2.z * v2.z + v2.w * v2.w))
                 + ((v3.x * v3.x + v3.y * v3.y) + (v3.z * v3.z + v3.w * v3.w));
        s1 += __shfl_xor(s1, 1); s2 += __shfl_xor(s2, 1);
        s1 += __shfl_xor(s1, 2); s2 += __shfl_xor(s2, 2);
        s1 += __shfl_xor(s1, 4); s2 += __shfl_xor(s2, 4);
        s1 += __shfl_xor(s1, 8); s2 += __shfl_xor(s2, 8);
        const float mean = s1 * (1.f / 256.f);
        const float rstd = rsqrtf(s2 * (1.f / 256.f) - mean * mean + kEps);
        const int c0 = e * 16;
        const float4 ga = *(const float4*)&lng[c0];
        const float4 gb = *(const float4*)&lng[c0 + 4];
        const float4 gc = *(const float4*)&lng[c0 + 8];
        const float4 gd = *(const float4*)&lng[c0 + 12];
        const float4 ba = *(const float4*)&lnb[c0];
        const float4 bb = *(const float4*)&lnb[c0 + 4];
        const float4 bc = *(const float4*)&lnb[c0 + 8];
        const float4 bd = *(const float4*)&lnb[c0 + 12];
        union { unsigned u4[4]; s16x8 s; } p0, p1;
        p0.u4[0] = pk2bf((v0.x - mean) * rstd * ga.x + ba.x,
                         (v0.y - mean) * rstd * ga.y + ba.y);
        p0.u4[1] = pk2bf((v0.z - mean) * rstd * ga.z + ba.z,
                         (v0.w - mean) * rstd * ga.w + ba.w);
        p0.u4[2] = pk2bf((v1.x - mean) * rstd * gb.x + bb.x,
                         (v1.y - mean) * rstd * gb.y + bb.y);
        p0.u4[3] = pk2bf((v1.z - mean) * rstd * gb.z + bb.z,
                         (v1.w - mean) * rstd * gb.w + bb.w);
        p1.u4[0] = pk2bf((v2.x - mean) * rstd * gc.x + bc.x,
                         (v2.y - mean) * rstd * gc.y + bc.y);
        p1.u4[1] = pk2bf((v2.z - mean) * rstd * gc.z + bc.z,
                         (v2.w - mean) * rstd * gc.w + bc.w);
        p1.u4[2] = pk2bf((v3.x - mean) * rstd * gd.x + bd.x,
                         (v3.y - mean) * rstd * gd.y + bd.y);
        p1.u4[3] = pk2bf((v3.z - mean) * rstd * gd.z + bd.z,
                         (v3.w - mean) * rstd * gd.w + bd.w);
        const int cg0 = e * 2, cg1 = e * 2 + 1;
        *(s16x8*)&dsA[r * 256 + ((cg0 ^ (r & 7)) << 3)] = p0.s;
        *(s16x8*)&dsA[r * 256 + ((cg1 ^ (r & 7)) << 3)] = p1.s;
    } else {
        const int r = tid >> 4, e = tid & 15;
        const ushort_t* hr = hin + (size_t)(m0 + r) * 256 + e * 16;
        #pragma unroll
        for (int i = 0; i < 2; i++) {
            const s16x8 v = *(const s16x8*)&hr[i * 8];
            const int cg = e * 2 + i;
            *(s16x8*)&dsA[r * 256 + ((cg ^ (r & 7)) << 3)] = v;
        }
    }
    __syncthreads();
    f32x4 acc[12] = {};
    const int cbase = wave * 192;
    for (int kt = 0; kt < 8; ++kt) {
        const int cg = kt * 4 + g;
        const s16x8 af = *(const s16x8*)&dsA[qi * 256 + ((cg ^ (qi & 7)) << 3)];
        #pragma unroll
        for (int nn = 0; nn < 12; ++nn) {
            const int wr = cbase + nn * 16 + qi;
            const s16x8 bf = *(const s16x8*)&W[(size_t)wr * 256 + kt * 32 + g * 8];
            acc[nn] = __builtin_amdgcn_mfma_f32_16x16x32_bf16(af, bf, acc[nn], 0, 0, 0);
        }
    }
    #pragma unroll
    for (int nn = 0; nn < 12; ++nn) {
        const int col = cbase + nn * 16 + qi;
        const float bv = bias[col];
        const int hh = (col & 255) >> 4, dd = col & 15;
        #pragma unroll
        for (int r = 0; r < 4; ++r) {
            const int gm = m0 + 4 * g + r;
            const int b = (gm >= kT) ? 1 : 0;
            const int ss = gm - b * kT;
            const size_t hoff = (((size_t)(b * 16 + hh)) * kT + ss) * 16 + dd;
            const float v = acc[nn][r] + bv;
            if (col < 256)      outQ[hoff] = f2bf(v * kQScale);
            else if (col < 512) outK[hoff] = f2bf(v);
            else                outV[hoff] = f2bf(v);
        }
    }
}

// ---------- fused combine + proj GEMM + residual (+ optional LN) --------
__global__ __launch_bounds__(256) void gemmcomb_kernel(
        const ushort_t* __restrict__ o_part, const float* __restrict__ l_part,
        const ushort_t* __restrict__ W, const float* __restrict__ bias,
        const float* __restrict__ res,
        const float* __restrict__ lng, const float* __restrict__ lnb,
        float* __restrict__ outf, ushort_t* __restrict__ outln) {
    __shared__ ushort_t dsA[16 * 256];
    __shared__ float ws1[4][16], ws2[4][16];
    const int tid = threadIdx.x;
    const int lane = tid & 63, wave = tid >> 6;
    const int qi = lane & 15, g = lane >> 4;
    const int wn = wave * 64;
    const int m0 = blockIdx.x * 16;

    {
        const int h = tid >> 4, r = tid & 15;
        const int gm = m0 + r;
        const int b = (gm >= kT) ? 1 : 0;
        const int t = gm - b * kT;
        float f[16] = {};
        float l = 0.f;
        #pragma unroll
        for (int p = 0; p < kSP; ++p) {
            const size_t sl_ = (size_t)((b * kSP + p) * 16 + h);
            l += l_part[sl_ * kT + t];
            const s16x8 v0 = *(const s16x8*)&o_part[(sl_ * kT + t) * 16];
            const s16x8 v1 = *(const s16x8*)&o_part[(sl_ * kT + t) * 16 + 8];
            #pragma unroll
            for (int j = 0; j < 8; j++) {
                f[j]     += bf2f((ushort_t)v0[j]);
                f[8 + j] += bf2f((ushort_t)v1[j]);
            }
        }
        const float li = 1.f / l;
        union { unsigned u4[4]; s16x8 s; } p0, p1;
        p0.u4[0] = pk2bf(f[0] * li, f[1] * li);
        p0.u4[1] = pk2bf(f[2] * li, f[3] * li);
        p0.u4[2] = pk2bf(f[4] * li, f[5] * li);
        p0.u4[3] = pk2bf(f[6] * li, f[7] * li);
        p1.u4[0] = pk2bf(f[8] * li, f[9] * li);
        p1.u4[1] = pk2bf(f[10] * li, f[11] * li);
        p1.u4[2] = pk2bf(f[12] * li, f[13] * li);
        p1.u4[3] = pk2bf(f[14] * li, f[15] * li);
        const int cg0 = h * 2, cg1 = h * 2 + 1;
        *(s16x8*)&dsA[r * 256 + ((cg0 ^ (r & 7)) << 3)] = p0.s;
        *(s16x8*)&dsA[r * 256 + ((cg1 ^ (r & 7)) << 3)] = p1.s;
    }
    __syncthreads();
    f32x4 acc[4] = {};
    for (int kt = 0; kt < 8; ++kt) {
        const int cg = kt * 4 + g;
        const s16x8 af = *(const s16x8*)&dsA[qi * 256 + ((cg ^ (qi & 7)) << 3)];
        #pragma unroll
        for (int nn = 0; nn < 4; ++nn) {
            const int wr = wn + nn * 16 + qi;
            const s16x8 bf = *(const s16x8*)&W[(size_t)wr * 256 + kt * 32 + g * 8];
            acc[nn] = __builtin_amdgcn_mfma_f32_16x16x32_bf16(af, bf, acc[nn], 0, 0, 0);
        }
    }
    float v[4][4];
    float s1[4] = {0.f, 0.f, 0.f, 0.f}, s2[4] = {0.f, 0.f, 0.f, 0.f};
    #pragma unroll
    for (int nn = 0; nn < 4; ++nn) {
        #pragma unroll
        for (int r = 0; r < 4; ++r) {
            const int row = 4 * g + r, col = wn + nn * 16 + qi;
            const size_t idx = (size_t)(m0 + row) * 256 + col;
            const float t = acc[nn][r] + bias[col] + res[idx];
            outf[idx] = t;
            v[nn][r] = t;
            s1[r] += t; s2[r] += t * t;
        }
    }
    if (outln) {
        #pragma unroll
        for (int r = 0; r < 4; ++r) {
            s1[r] += __shfl_xor(s1[r], 1); s2[r] += __shfl_xor(s2[r], 1);
            s1[r] += __shfl_xor(s1[r], 2); s2[r] += __shfl_xor(s2[r], 2);
            s1[r] += __shfl_xor(s1[r], 4); s2[r] += __shfl_xor(s2[r], 4);
            s1[r] += __shfl_xor(s1[r], 8); s2[r] += __shfl_xor(s2[r], 8);
        }
        if (qi == 0) {
            #pragma unroll
            for (int r = 0; r < 4; ++r) { ws1[wave][4 * g + r] = s1[r]; ws2[wave][4 * g + r] = s2[r]; }
        }
        __syncthreads();
        #pragma unroll
        for (int r = 0; r < 4; ++r) {
            const int row = 4 * g + r;
            const float S1 = ws1[0][row] + ws1[1][row] + ws1[2][row] + ws1[3][row];
            const float S2 = ws2[0][row] + ws2[1][row] + ws2[2][row] + ws2[3][row];
            const float mean = S1 * (1.f / 256.f);
            const float rstd = rsqrtf(S2 * (1.f / 256.f) - mean * mean + kEps);
            #pragma unroll
            for (int nn = 0; nn < 4; ++nn) {
                const int col = wn + nn * 16 + qi;
                outln[(size_t)(m0 + row) * 256 + col] =
                    f2bf((v[nn][r] - mean) * rstd * lng[col] + lnb[col]);
            }
        }
    }
}

// ---------- fused memory-bank read + LN3 ----------
__global__ __launch_bounds__(256) void memread_kernel(
        const float* __restrict__ x2, const ushort_t* __restrict__ wRead,
        const float* __restrict__ read_b, const ushort_t* __restrict__ wMemT,
        const float* __restrict__ lng, const float* __restrict__ lnb,
        float* __restrict__ xout, ushort_t* __restrict__ outln) {
    __shared__ ushort_t dsP[16 * 256];
    __shared__ float lsum[4][16];
    __shared__ float lt[16];
    __shared__ float ws1[4][16], ws2[4][16];
    const int tid = threadIdx.x;
    const int lane = tid & 63, wave = tid >> 6;
    const int qi = lane & 15, g = lane >> 4;
    const int wn = wave * 64;
    const int m0 = blockIdx.x * 16;

    {
        const int r = tid >> 4, e = tid & 15;
        const float* xr = x2 + (size_t)(m0 + r) * 256 + e * 16;
        #pragma unroll
        for (int i = 0; i < 2; i++) {
            const float4 va = *(const float4*)&xr[i * 8];
            const float4 vb = *(const float4*)&xr[i * 8 + 4];
            union { unsigned u4[4]; s16x8 s; } pu;
            pu.u4[0] = pk2bf(va.x, va.y);
            pu.u4[1] = pk2bf(va.z, va.w);
            pu.u4[2] = pk2bf(vb.x, vb.y);
            pu.u4[3] = pk2bf(vb.z, vb.w);
            const int cg = e * 2 + i;
            *(s16x8*)&dsP[r * 256 + ((cg ^ (r & 7)) << 3)] = pu.s;
        }
    }
    __syncthreads();
    f32x4 acc[4] = {};
    for (int kt = 0; kt < 8; ++kt) {
        const int cg = kt * 4 + g;
        const s16x8 af = *(const s16x8*)&dsP[qi * 256 + ((cg ^ (qi & 7)) << 3)];
        #pragma unroll
        for (int nn = 0; nn < 4; ++nn) {
            const int wr = wn + nn * 16 + qi;
            const s16x8 bf = *(const s16x8*)&wRead[(size_t)wr * 256 + kt * 32 + g * 8];
            acc[nn] = __builtin_amdgcn_mfma_f32_16x16x32_bf16(af, bf, acc[nn], 0, 0, 0);
        }
    }
    float p[4][4];
    float rs[4] = {0.f, 0.f, 0.f, 0.f};
    #pragma unroll
    for (int nn = 0; nn < 4; ++nn) {
        const float bb = read_b[wn + nn * 16 + qi];
        #pragma unroll
        for (int r = 0; r < 4; ++r) {
            p[nn][r] = __expf(acc[nn][r] + bb);
            rs[r] += p[nn][r];
        }
    }
    #pragma unroll
    for (int r = 0; r < 4; ++r) {
        rs[r] += __shfl_xor(rs[r], 1);
        rs[r] += __shfl_xor(rs[r], 2);
        rs[r] += __shfl_xor(rs[r], 4);
        rs[r] += __shfl_xor(rs[r], 8);
    }
    __syncthreads();
    if (qi == 0) {
        #pragma unroll
        for (int r = 0; r < 4; ++r) lsum[wave][4 * g + r] = rs[r];
    }
    #pragma unroll
    for (int nn = 0; nn < 4; ++nn) {
        #pragma unroll
        for (int r = 0; r < 4; ++r) {
            const int row = 4 * g + r, col = wn + nn * 16 + qi;
            const int cg = col >> 3, e = col & 7;
            dsP[row * 256 + ((cg ^ (row & 7)) << 3) + e] = f2bf(p[nn][r]);
        }
    }
    __syncthreads();
    if (tid < 16)
        lt[tid] = 1.f / (lsum[0][tid] + lsum[1][tid] + lsum[2][tid] + lsum[3][tid]);
    __syncthreads();
    f32x4 acc2[4] = {};
    for (int kt = 0; kt < 8; ++kt) {
        const int cg = kt * 4 + g;
        const s16x8 af = *(const s16x8*)&dsP[qi * 256 + ((cg ^ (qi & 7)) << 3)];
        #pragma unroll
        for (int nn = 0; nn < 4; ++nn) {
            const int wr = wn + nn * 16 + qi;
            const s16x8 bf = *(const s16x8*)&wMemT[(size_t)wr * 256 + kt * 32 + g * 8];
            acc2[nn] = __builtin_amdgcn_mfma_f32_16x16x32_bf16(af, bf, acc2[nn], 0, 0, 0);
        }
    }
    float xo[4][4];
    float s1[4] = {0.f, 0.f, 0.f, 0.f}, s2[4] = {0.f, 0.f, 0.f, 0.f};
    #pragma unroll
    for (int nn = 0; nn < 4; ++nn) {
        #pragma unroll
        for (int r = 0; r < 4; ++r) {
            const int row = 4 * g + r;
            const size_t idx = (size_t)(m0 + row) * 256 + wn + nn * 16 + qi;
            const float t = acc2[nn][r] * lt[row] + x2[idx];
            xout[idx] = t;
            xo[nn][r] = t;
            s1[r] += t; s2[r] += t * t;
        }
    }
    #pragma unroll
    for (int r = 0; r < 4; ++r) {
        s1[r] += __shfl_xor(s1[r], 1); s2[r] += __shfl_xor(s2[r], 1);
        s1[r] += __shfl_xor(s1[r], 2); s2[r] += __shfl_xor(s2[r], 2);
        s1[r] += __shfl_xor(s1[r], 4); s2[r] += __shfl_xor(s2[r], 4);
        s1[r] += __shfl_xor(s1[r], 8); s2[r] += __shfl_xor(s2[r], 8);
    }
    if (qi == 0) {
        #pragma unroll
        for (int r = 0; r < 4; ++r) { ws1[wave][4 * g + r] = s1[r]; ws2[wave][4 * g + r] = s2[r]; }
    }
    __syncthreads();
    #pragma unroll
    for (int r = 0; r < 4; ++r) {
        const int row = 4 * g + r;
        const float S1 = ws1[0][row] + ws1[1][row] + ws1[2][row] + ws1[3][row];
        const float S2 = ws2[0][row] + ws2[1][row] + ws2[2][row] + ws2[3][row];
        const float mean = S1 * (1.f / 256.f);
        const float rstd = rsqrtf(S2 * (1.f / 256.f) - mean * mean + kEps);
        #pragma unroll
        for (int nn = 0; nn < 4; ++nn) {
            const int col = wn + nn * 16 + qi;
            outln[(size_t)(m0 + row) * 256 + col] =
                f2bf((xo[nn][r] - mean) * rstd * lng[col] + lnb[col]);
        }
    }
}

// ---------- flash MFMA attention: kSP=5, QBLK=128, prefetched tr_read PV --
template <bool kAff>
__global__ __launch_bounds__(512) void attn_mfma_kernel(
        const ushort_t* __restrict__ q, const ushort_t* __restrict__ kbuf,
        const ushort_t* __restrict__ vbuf, ushort_t* __restrict__ o_part,
        float* __restrict__ l_part,
        const float* __restrict__ affinity, const int* __restrict__ did) {
    __shared__ ushort_t ldsK[SBLK * KPITCH];   // [s][d]  13824 B
    __shared__ ushort_t ldsV[SBLK * 16];       // [s][d]   9216 B
    const int tid  = threadIdx.x;
    const int bid  = blockIdx.x;
    const int w    = (bid & 7) * 220 + (bid >> 3);
    const int slice = w / 11;
    const int ttile = w - slice * 11;
    const int h    = slice & 15;
    const int z    = slice >> 4;
    const int b    = (z >= 5) ? 1 : 0;
    const int sp   = z - b * 5;
    const int t0   = ttile * 128;
    const int s0   = sp * kSLen;
    const int lane = tid & 63;
    const int wave = tid >> 6;
    const int g    = lane >> 4;
    const int qi   = lane & 15;

    const int tq  = t0 + wave * 16 + qi;
    const int tqc = min(tq, kT - 1);
    const ushort_t* qhb = q + (size_t)(b * 16 + h) * kT * 16;
    s16x8 qb = {0, 0, 0, 0, 0, 0, 0, 0};
    if (g < 2) qb = *(const s16x8*)&qhb[(size_t)tqc * 16 + g * 8];
    const float* ar = nullptr;
    if (kAff) ar = affinity + (size_t)did[b * kT + tqc] * kT;

    const ushort_t* kb  = kbuf + (size_t)(b * 16 + h) * kT * 16;
    const ushort_t* vbp = vbuf + (size_t)(b * 16 + h) * kT * 16;
    for (int i = tid; i < SBLK * 2; i += 512) {
        const int sl = i >> 1, hf = i & 1;
        const int sg = min(s0 + sl, kT - 1);
        *(s16x8*)&ldsK[sl * KPITCH + hf * 8] =
            *(const s16x8*)&kb[(size_t)sg * 16 + hf * 8];
        *(s16x8*)&ldsV[sl * 16 + hf * 8] =
            *(const s16x8*)&vbp[(size_t)sg * 16 + hf * 8];
    }
    __syncthreads();

    f32x4 acc = {0.f, 0.f, 0.f, 0.f};
    float lrun = 0.f;
    const unsigned vaddr = (unsigned)(size_t)(&ldsV[0]) + lane * 8;
    s16x4 va0, va1;
    asm volatile("ds_read_b64_tr_b16 %0, %2\n\t"
                 "ds_read_b64_tr_b16 %1, %2 offset:512"
                 : "=&v"(va0), "=&v"(va1) : "v"(vaddr));

    #pragma unroll
    for (int c = 0; c < SBLK / 32; ++c) {
        const int sl0 = c * 32;
        const bool tail = (c == 8);
        const s16x8 ka0 = *(const s16x8*)&ldsK[(sl0 + qi) * KPITCH + (g & 1) * 8];
        const s16x8 ka1 = *(const s16x8*)&ldsK[(sl0 + 16 + qi) * KPITCH + (g & 1) * 8];
        const f32x4 z4 = {0.f, 0.f, 0.f, 0.f};
        f32x4 d0 = __builtin_amdgcn_mfma_f32_16x16x32_bf16(ka0, qb, z4, 0, 0, 0);
        f32x4 d1 = __builtin_amdgcn_mfma_f32_16x16x32_bf16(ka1, qb, z4, 0, 0, 0);
        float sv[8];
        #pragma unroll
        for (int r = 0; r < 4; r++) { sv[r] = d0[r]; sv[4 + r] = d1[r]; }
        if (kAff) {
            if (!tail) {
                const float4 a0 = *(const float4*)&ar[s0 + sl0 + 4 * g];
                const float4 a1 = *(const float4*)&ar[s0 + sl0 + 16 + 4 * g];
                sv[0] += kAffScale * a0.x; sv[1] += kAffScale * a0.y;
                sv[2] += kAffScale * a0.z; sv[3] += kAffScale * a0.w;
                sv[4] += kAffScale * a1.x; sv[5] += kAffScale * a1.y;
                sv[6] += kAffScale * a1.z; sv[7] += kAffScale * a1.w;
            } else {
                #pragma unroll
                for (int jj = 0; jj < 8; jj++) {
                    const int s_ = s0 + sl0 + 16 * (jj >> 2) + 4 * g + (jj & 3);
                    sv[jj] += kAffScale * ar[min(s_, kT - 1)];
                }
            }
        }
        float pv[8];
        #pragma unroll
        for (int jj = 0; jj < 8; jj++) pv[jj] = fast_exp2(sv[jj]);
        if (tail && g >= 2) { pv[4] = 0.f; pv[5] = 0.f; pv[6] = 0.f; pv[7] = 0.f; }
        lrun += ((pv[0] + pv[1]) + (pv[2] + pv[3])) + ((pv[4] + pv[5]) + (pv[6] + pv[7]));
        union { unsigned u[4]; s16x8 s; } pu;
        pu.u[0] = pk2bf(pv[0], pv[1]);
        pu.u[1] = pk2bf(pv[2], pv[3]);
        pu.u[2] = pk2bf(pv[4], pv[5]);
        pu.u[3] = pk2bf(pv[6], pv[7]);
        asm volatile("s_waitcnt lgkmcnt(0)" ::: "memory");
        __builtin_amdgcn_sched_barrier(0);   // rule 18
        s16x8 af;
        #pragma unroll
        for (int j = 0; j < 4; j++) { af[j] = va0[j]; af[4 + j] = va1[j]; }
        acc = __builtin_amdgcn_mfma_f32_16x16x32_bf16(af, pu.s, acc, 0, 0, 0);
        if (c < SBLK / 32 - 1) {
            asm volatile("ds_read_b64_tr_b16 %0, %2\n\t"
                         "ds_read_b64_tr_b16 %1, %2 offset:512"
                         : "=&v"(va0), "=&v"(va1) : "v"(vaddr + (sl0 + 32) * 32));
        }
    }
    lrun += __shfl_xor(lrun, 16);
    lrun += __shfl_xor(lrun, 32);
    const int slice_id = (b * kSP + sp) * 16 + h;
    if (lane < 16 && tq < kT)
        l_part[(size_t)slice_id * kT + tq] = lrun;
    ushort_t* ob = o_part + (size_t)slice_id * kT * 16;
    s16x4 ov;
    #pragma unroll
    for (int r = 0; r < 4; r++) ov[r] = (short)f2bf(acc[r]);
    if (tq < kT) *(s16x4*)&ob[(size_t)tq * 16 + 4 * g] = ov;
}

}  // namespace

extern "C" void kernel_launch(void* const* d_in, const int* in_sizes, int n_in,
                              void* d_out, int out_size, void* d_ws, size_t ws_size,
                              hipStream_t stream) {
    const float* x          = (const float*)d_in[0];
    const int*   did        = (const int*)d_in[1];
    const float* in_proj_w  = (const float*)d_in[2];
    const float* in_proj_b  = (const float*)d_in[3];
    const float* out_proj_w = (const float*)d_in[4];
    const float* out_proj_b = (const float*)d_in[5];
    const float* ln1_g = (const float*)d_in[6];
    const float* ln1_b = (const float*)d_in[7];
    const float* ln2_g = (const float*)d_in[8];
    const float* ln2_b = (const float*)d_in[9];
    const float* ln3_g = (const float*)d_in[10];
    const float* ln3_b = (const float*)d_in[11];
    const float* gq_w = (const float*)d_in[12];
    const float* gq_b = (const float*)d_in[13];
    const float* gk_w = (const float*)d_in[14];
    const float* gk_b = (const float*)d_in[15];
    const float* gv_w = (const float*)d_in[16];
    const float* gv_b = (const float*)d_in[17];
    const float* go_w = (const float*)d_in[18];
    const float* go_b = (const float*)d_in[19];
    const float* affinity = (const float*)d_in[20];
    const float* mem_bank = (const float*)d_in[21];
    const float* read_w   = (const float*)d_in[22];
    const float* read_b   = (const float*)d_in[23];
    const float* ffn_w1 = (const float*)d_in[24];
    const float* ffn_b1 = (const float*)d_in[25];
    const float* ffn_w2 = (const float*)d_in[26];
    const float* ffn_b2 = (const float*)d_in[27];

    // ---- workspace layout (byte offsets; lifetimes hand-verified) ----
    char* wsb = (char*)d_ws;
    ushort_t* o_part  = (ushort_t*)(wsb + 0);          // [160][kT][16] bf16
    float*    l_part  = (float*)(wsb + 7168000);       // [160][kT] fp32
    ushort_t* ff116   = (ushort_t*)(wsb + 8064000);    // [BT,1024] (FFN phase)
    float*    bufD    = (float*)(wsb + 13798400);      // fp32 x2/x3
    ushort_t* bufA16  = (ushort_t*)(wsb + 16665600);   // bf16 LN out
    float*    bufD2   = (float*)(wsb + 18099200);      // fp32 x1
    ushort_t* bufQ16  = (ushort_t*)(wsb + 20966400);   // [B][H][T][16] (xQScale)
    ushort_t* bufK16  = (ushort_t*)(wsb + 22400000);   // [B][H][T][16]
    ushort_t* bufV16  = (ushort_t*)(wsb + 23833600);   // [B][H][T][16]
    ushort_t* wdst    = (ushort_t*)(wsb + 26700800);   // bf16 weights
    float*    gqkvb   = (float*)(wsb + 29191168);      // [768]

    const ushort_t* wQKV1 = wdst;
    const ushort_t* wG    = wdst + 196608;
    const ushort_t* wO    = wdst + 393216;
    const ushort_t* wGO   = wdst + 458752;
    const ushort_t* wF1   = wdst + 524288;
    const ushort_t* wF2   = wdst + 786432;
    const ushort_t* wRead = wdst + 1048576;
    const ushort_t* wMemT = wdst + 1114112;

    const dim3 blk(256);
    const int MT = (kBT + 63) / 64;        // 44
    const dim3 g_c(MT, 4), g_ff(MT, 16);
    const dim3 g_row(kBT / 16);            // 175
    const dim3 g_at(11 * kH * kB * kSP);   // 1760 = 8 * 220

    convert_kernel<<<609, blk, 0, stream>>>(in_proj_w, gq_w, gk_w, gv_w, out_proj_w,
                                            go_w, ffn_w1, ffn_w2, read_w, mem_bank,
                                            gq_b, gk_b, gv_b, wdst, gqkvb);
    // 1+2. qkv = LN1(x) @ in_proj^T + b -> head-major Q(xQScale)/K/V
    qkvln_kernel<<<g_row, blk, 0, stream>>>(x, nullptr, ln1_g, ln1_b,
                                            wQKV1, in_proj_b,
                                            bufQ16, bufK16, bufV16);
    // 3. MHA partials
    attn_mfma_kernel<false><<<g_at, dim3(512), 0, stream>>>(bufQ16, bufK16, bufV16,
                                                            o_part, l_part,
                                                            nullptr, nullptr);
    // 4+5. x1 = x + combine(o) @ out_proj^T + b (fp32) + LN2(x1) bf16, fused
    gemmcomb_kernel<<<g_row, blk, 0, stream>>>(o_part, l_part, wO, out_proj_b,
                                               x, ln2_g, ln2_b, bufD2, bufA16);
    // 6. graph qkv (bf16 direct path)
    qkvln_kernel<<<g_row, blk, 0, stream>>>(nullptr, bufA16, nullptr, nullptr,
                                            wG, gqkvb,
                                            bufQ16, bufK16, bufV16);
    // 7. graph attention partials
    attn_mfma_kernel<true><<<g_at, dim3(512), 0, stream>>>(bufQ16, bufK16, bufV16,
                                                           o_part, l_part,
                                                           affinity, did);
    // 8. x2 = x1 + combine(o2) @ go^T + b -> bufD fp32 (no LN)
    gemmcomb_kernel<<<g_row, blk, 0, stream>>>(o_part, l_part, wGO, go_b,
                                               bufD2, nullptr, nullptr,
                                               bufD, nullptr);
    // 9+10. x3 = x2 + softmax(x2@read_w^T+rb) @ mem_bank (in place) + LN3 fused
    memread_kernel<<<g_row, blk, 0, stream>>>(bufD, wRead, read_b, wMemT,
                                              ln3_g, ln3_b, bufD, bufA16);
    // 11. ff1 = gelu(LN3 @ w1^T + b1) -> bf16 [BT,1024]  (64x64-tile GEMM)
    gemm16_kernel<<<g_ff, blk, 0, stream>>>(bufA16, wF1, ffn_b1, nullptr,
                                            nullptr, ff116, kBT, kFF, kC, kFF, 1);
    // 12. out = x3 + ff1 @ w2^T + b2
    gemm16_kernel<<<g_c, blk, 0, stream>>>(ff116, wF2, ffn_b2, bufD,
                                           (float*)d_out, nullptr, kBT, kC, kFF, kC, 0);
}

// Round 20
// 143.412 us; speedup vs baseline: 1.2146x; 1.0813x over previous
//
#include <hip/hip_runtime.h>
#include <hip/hip_bf16.h>
#include <math.h>

namespace {

typedef __attribute__((ext_vector_type(4))) float f32x4;
typedef __attribute__((ext_vector_type(8))) short s16x8;
typedef __attribute__((ext_vector_type(4))) short s16x4;
typedef unsigned short ushort_t;

constexpr int kB = 2, kT = 1400, kC = 256, kH = 16, kFF = 1024;
constexpr int kBT = kB * kT;
constexpr float kEps = 1e-5f;
constexpr int kSP = 5;               // s-split (5*280 = 1400)
constexpr int kSLen = 280;
constexpr int SBLK = 288;            // 9 chunks of 32
constexpr int KPITCH = 24;           // K row pitch (48 B)
constexpr float kQScale   = 0.25f * 1.4426950408889634f;   // 1/sqrt(D) * log2(e)
constexpr float kAffScale = 0.1f * 1.4426950408889634f;    // 0.1 * log2(e)

__device__ __forceinline__ ushort_t f2bf(float f) {
    unsigned u = __float_as_uint(f);
    u += 0x7fffu + ((u >> 16) & 1u);
    return (ushort_t)(u >> 16);
}
__device__ __forceinline__ float bf2f(ushort_t u) {
    return __uint_as_float(((unsigned)u) << 16);
}
__device__ __forceinline__ unsigned pk2bf(float a, float b) {
    __hip_bfloat162 t = __float22bfloat162_rn(make_float2(a, b));
    union { __hip_bfloat162 h; unsigned u; } cv; cv.h = t;
    return cv.u;
}
__device__ __forceinline__ float fast_exp2(float x) {
    float r;
    asm("v_exp_f32 %0, %1" : "=v"(r) : "v"(x));
    return r;
}

// ---------- weight convert/pack ----------
__global__ __launch_bounds__(256) void convert_kernel(
        const float* __restrict__ in_proj_w, const float* __restrict__ gq_w,
        const float* __restrict__ gk_w, const float* __restrict__ gv_w,
        const float* __restrict__ out_proj_w, const float* __restrict__ go_w,
        const float* __restrict__ ffn_w1, const float* __restrict__ ffn_w2,
        const float* __restrict__ read_w, const float* __restrict__ mem_bank,
        const float* __restrict__ gq_b, const float* __restrict__ gk_b,
        const float* __restrict__ gv_b,
        ushort_t* __restrict__ wdst, float* __restrict__ gqkvb) {
    const int bid = blockIdx.x, tid = threadIdx.x;
    if (bid == 608) {
        gqkvb[tid] = gq_b[tid];
        gqkvb[256 + tid] = gk_b[tid];
        gqkvb[512 + tid] = gv_b[tid];
        return;
    }
    const int u0 = (bid * 256 + tid) * 8;
    if (u0 >= 1114112) {  // mem_bank transpose
        #pragma unroll
        for (int j = 0; j < 8; j++) {
            const int d = u0 - 1114112 + j;
            wdst[1114112 + d] = f2bf(mem_bank[(d & 255) * 256 + (d >> 8)]);
        }
        return;
    }
    const float* src; int off;
    if      (u0 < 196608)  { src = in_proj_w;  off = u0; }
    else if (u0 < 262144)  { src = gq_w;       off = u0 - 196608; }
    else if (u0 < 327680)  { src = gk_w;       off = u0 - 262144; }
    else if (u0 < 393216)  { src = gv_w;       off = u0 - 327680; }
    else if (u0 < 458752)  { src = out_proj_w; off = u0 - 393216; }
    else if (u0 < 524288)  { src = go_w;       off = u0 - 458752; }
    else if (u0 < 786432)  { src = ffn_w1;     off = u0 - 524288; }
    else if (u0 < 1048576) { src = ffn_w2;     off = u0 - 786432; }
    else                   { src = read_w;     off = u0 - 1048576; }
    #pragma unroll
    for (int j = 0; j < 8; j++) wdst[u0 + j] = f2bf(src[off + j]);
}

// ---------- LayerNorm: single-pass (sum+sumsq in one shfl tree) ----------
__global__ __launch_bounds__(256) void ln_kernel(
        const float* __restrict__ x, const float* __restrict__ g,
        const float* __restrict__ b, ushort_t* __restrict__ out) {
    __shared__ float red[10];
    const int row = blockIdx.x, tid = threadIdx.x;
    const float v = x[row * kC + tid];
    float s1 = v, s2 = v * v;
    #pragma unroll
    for (int off = 32; off > 0; off >>= 1) {
        s1 += __shfl_down(s1, off);
        s2 += __shfl_down(s2, off);
    }
    if ((tid & 63) == 0) { red[tid >> 6] = s1; red[4 + (tid >> 6)] = s2; }
    __syncthreads();
    if (tid == 0) {
        red[8] = red[0] + red[1] + red[2] + red[3];
        red[9] = red[4] + red[5] + red[6] + red[7];
    }
    __syncthreads();
    const float mean = red[8] * (1.f / kC);
    const float var = red[9] * (1.f / kC) - mean * mean;
    out[row * kC + tid] = f2bf((v - mean) * rsqrtf(var + kEps) * g[tid] + b[tid]);
}

// ---------- bf16 MFMA GEMM: out[m,n] = A[M,K] @ W[N,K]^T + bias ----------
// mode 0: row-major outf/outb. mode 1: qkv-split head-major Q(xQScale)/K/V.
__global__ __launch_bounds__(256) void gemm16_kernel(
        const ushort_t* __restrict__ A, const ushort_t* __restrict__ W,
        const float* __restrict__ bias, const float* __restrict__ res,
        float* __restrict__ outf, ushort_t* __restrict__ outb,
        ushort_t* __restrict__ outK, ushort_t* __restrict__ outV,
        int M, int N, int K, int ldo, int act, int mode) {
    __shared__ ushort_t dsA[64 * 64];
    __shared__ ushort_t dsW[64 * 64];
    const int tid = threadIdx.x;
    const int lane = tid & 63, wave = tid >> 6;
    const int qi = lane & 15, g = lane >> 4;
    const int wm = (wave >> 1) * 32, wn = (wave & 1) * 32;
    const int m0 = blockIdx.x * 64, n0 = blockIdx.y * 64;

    f32x4 acc[2][2] = {};
    for (int kt = 0; kt < K; kt += 64) {
        __syncthreads();
        #pragma unroll
        for (int j = 0; j < 2; ++j) {
            const int u = tid + j * 256;          // 0..511
            const int row = u >> 3, c = u & 7;
            const int cs = c ^ (row & 7);
            const int gmA = min(m0 + row, M - 1);
            *(s16x8*)&dsA[row * 64 + cs * 8] =
                *(const s16x8*)&A[(size_t)gmA * K + kt + c * 8];
            *(s16x8*)&dsW[row * 64 + cs * 8] =
                *(const s16x8*)&W[(size_t)(n0 + row) * K + kt + c * 8];
        }
        __syncthreads();
        #pragma unroll
        for (int kk = 0; kk < 2; ++kk) {
            s16x8 af[2], bf[2];
            #pragma unroll
            for (int f = 0; f < 2; ++f) {
                const int r = wm + f * 16 + qi;
                af[f] = *(const s16x8*)&dsA[r * 64 + (((kk * 4 + g) ^ (r & 7)) * 8)];
            }
            #pragma unroll
            for (int nn = 0; nn < 2; ++nn) {
                const int r = wn + nn * 16 + qi;
                bf[nn] = *(const s16x8*)&dsW[r * 64 + (((kk * 4 + g) ^ (r & 7)) * 8)];
            }
            #pragma unroll
            for (int f = 0; f < 2; ++f)
                #pragma unroll
                for (int nn = 0; nn < 2; ++nn)
                    acc[f][nn] = __builtin_amdgcn_mfma_f32_16x16x32_bf16(
                        af[f], bf[nn], acc[f][nn], 0, 0, 0);
        }
    }
    #pragma unroll
    for (int f = 0; f < 2; ++f) {
        #pragma unroll
        for (int r = 0; r < 4; ++r) {
            const int gm = m0 + wm + f * 16 + g * 4 + r;
            if (gm >= M) continue;
            #pragma unroll
            for (int nn = 0; nn < 2; ++nn) {
                const int gn = n0 + wn + nn * 16 + qi;
                float v = acc[f][nn][r];
                if (bias) v += bias[gn];
                if (act == 1) v = 0.5f * v * (1.f + erff(v * 0.70710678f));
                if (res) v += res[(size_t)gm * ldo + gn];
                if (mode == 1) {
                    const int bb = (gm >= kT) ? 1 : 0;
                    const int ss = gm - bb * kT;
                    const int hh = (gn & 255) >> 4, dd = gn & 15;
                    const size_t hoff = (((size_t)(bb * 16 + hh)) * kT + ss) * 16 + dd;
                    if (gn < 256)      outb[hoff] = f2bf(v * kQScale);  // Q, exp2-fold
                    else if (gn < 512) outK[hoff] = f2bf(v);
                    else               outV[hoff] = f2bf(v);
                } else {
                    if (outf) outf[(size_t)gm * ldo + gn] = v;
                    if (outb) outb[(size_t)gm * ldo + gn] = f2bf(v);
                }
            }
        }
    }
}

// ---------- fused combine + proj GEMM + residual (+ optional LN) --------
// 16 complete rows per block. A = combine(o_part,l_part) built in staging.
// x' = res + A @ W^T + bias (fp32 out); if outln: outln = LN(x') bf16.
__global__ __launch_bounds__(256) void gemmcomb_kernel(
        const ushort_t* __restrict__ o_part, const float* __restrict__ l_part,
        const ushort_t* __restrict__ W, const float* __restrict__ bias,
        const float* __restrict__ res,
        const float* __restrict__ lng, const float* __restrict__ lnb,
        float* __restrict__ outf, ushort_t* __restrict__ outln) {
    __shared__ ushort_t dsA[16 * 256];
    __shared__ float ws1[4][16], ws2[4][16];
    const int tid = threadIdx.x;
    const int lane = tid & 63, wave = tid >> 6;
    const int qi = lane & 15, g = lane >> 4;
    const int wn = wave * 64;
    const int m0 = blockIdx.x * 16;

    // staging: thread = (h = tid>>4, r = tid&15); combine 5 slice-partials
    {
        const int h = tid >> 4, r = tid & 15;
        const int gm = m0 + r;
        const int b = (gm >= kT) ? 1 : 0;
        const int t = gm - b * kT;
        float f[16] = {};
        float l = 0.f;
        #pragma unroll
        for (int p = 0; p < kSP; ++p) {
            const size_t sl_ = (size_t)((b * kSP + p) * 16 + h);
            l += l_part[sl_ * kT + t];
            const s16x8 v0 = *(const s16x8*)&o_part[(sl_ * kT + t) * 16];
            const s16x8 v1 = *(const s16x8*)&o_part[(sl_ * kT + t) * 16 + 8];
            #pragma unroll
            for (int j = 0; j < 8; j++) {
                f[j]     += bf2f((ushort_t)v0[j]);
                f[8 + j] += bf2f((ushort_t)v1[j]);
            }
        }
        const float li = 1.f / l;
        union { unsigned u4[4]; s16x8 s; } p0, p1;
        p0.u4[0] = pk2bf(f[0] * li, f[1] * li);
        p0.u4[1] = pk2bf(f[2] * li, f[3] * li);
        p0.u4[2] = pk2bf(f[4] * li, f[5] * li);
        p0.u4[3] = pk2bf(f[6] * li, f[7] * li);
        p1.u4[0] = pk2bf(f[8] * li, f[9] * li);
        p1.u4[1] = pk2bf(f[10] * li, f[11] * li);
        p1.u4[2] = pk2bf(f[12] * li, f[13] * li);
        p1.u4[3] = pk2bf(f[14] * li, f[15] * li);
        const int cg0 = h * 2, cg1 = h * 2 + 1;
        *(s16x8*)&dsA[r * 256 + ((cg0 ^ (r & 7)) << 3)] = p0.s;
        *(s16x8*)&dsA[r * 256 + ((cg1 ^ (r & 7)) << 3)] = p1.s;
    }
    __syncthreads();
    f32x4 acc[4] = {};
    for (int kt = 0; kt < 8; ++kt) {
        const int cg = kt * 4 + g;
        const s16x8 af = *(const s16x8*)&dsA[qi * 256 + ((cg ^ (qi & 7)) << 3)];
        #pragma unroll
        for (int nn = 0; nn < 4; ++nn) {
            const int wr = wn + nn * 16 + qi;
            const s16x8 bf = *(const s16x8*)&W[(size_t)wr * 256 + kt * 32 + g * 8];
            acc[nn] = __builtin_amdgcn_mfma_f32_16x16x32_bf16(af, bf, acc[nn], 0, 0, 0);
        }
    }
    // epilogue: v = acc + bias + res -> outf; optional per-row LN
    float v[4][4];
    float s1[4] = {0.f, 0.f, 0.f, 0.f}, s2[4] = {0.f, 0.f, 0.f, 0.f};
    #pragma unroll
    for (int nn = 0; nn < 4; ++nn) {
        #pragma unroll
        for (int r = 0; r < 4; ++r) {
            const int row = 4 * g + r, col = wn + nn * 16 + qi;
            const size_t idx = (size_t)(m0 + row) * 256 + col;
            const float t = acc[nn][r] + bias[col] + res[idx];
            outf[idx] = t;
            v[nn][r] = t;
            s1[r] += t; s2[r] += t * t;
        }
    }
    if (outln) {
        #pragma unroll
        for (int r = 0; r < 4; ++r) {
            s1[r] += __shfl_xor(s1[r], 1); s2[r] += __shfl_xor(s2[r], 1);
            s1[r] += __shfl_xor(s1[r], 2); s2[r] += __shfl_xor(s2[r], 2);
            s1[r] += __shfl_xor(s1[r], 4); s2[r] += __shfl_xor(s2[r], 4);
            s1[r] += __shfl_xor(s1[r], 8); s2[r] += __shfl_xor(s2[r], 8);
        }
        if (qi == 0) {
            #pragma unroll
            for (int r = 0; r < 4; ++r) { ws1[wave][4 * g + r] = s1[r]; ws2[wave][4 * g + r] = s2[r]; }
        }
        __syncthreads();
        #pragma unroll
        for (int r = 0; r < 4; ++r) {
            const int row = 4 * g + r;
            const float S1 = ws1[0][row] + ws1[1][row] + ws1[2][row] + ws1[3][row];
            const float S2 = ws2[0][row] + ws2[1][row] + ws2[2][row] + ws2[3][row];
            const float mean = S1 * (1.f / 256.f);
            const float rstd = rsqrtf(S2 * (1.f / 256.f) - mean * mean + kEps);
            #pragma unroll
            for (int nn = 0; nn < 4; ++nn) {
                const int col = wn + nn * 16 + qi;
                outln[(size_t)(m0 + row) * 256 + col] =
                    f2bf((v[nn][r] - mean) * rstd * lng[col] + lnb[col]);
            }
        }
    }
}

// ---------- fused memory-bank read + LN3 ----------
// x3 = x2 + softmax(x2@Rw^T+rb) @ M (fp32, in place); outln = LN3(x3) bf16.
__global__ __launch_bounds__(256) void memread_kernel(
        const float* __restrict__ x2, const ushort_t* __restrict__ wRead,
        const float* __restrict__ read_b, const ushort_t* __restrict__ wMemT,
        const float* __restrict__ lng, const float* __restrict__ lnb,
        float* __restrict__ xout, ushort_t* __restrict__ outln) {
    __shared__ ushort_t dsP[16 * 256];   // x2 bf16, then P (8 KB)
    __shared__ float lsum[4][16];
    __shared__ float lt[16];
    __shared__ float ws1[4][16], ws2[4][16];
    const int tid = threadIdx.x;
    const int lane = tid & 63, wave = tid >> 6;
    const int qi = lane & 15, g = lane >> 4;
    const int wn = wave * 64;
    const int m0 = blockIdx.x * 16;

    // stage x2 rows -> bf16, swizzled
    {
        const int r = tid >> 4, e = tid & 15;
        const float* xr = x2 + (size_t)(m0 + r) * 256 + e * 16;
        #pragma unroll
        for (int i = 0; i < 2; i++) {
            const float4 va = *(const float4*)&xr[i * 8];
            const float4 vb = *(const float4*)&xr[i * 8 + 4];
            union { unsigned u4[4]; s16x8 s; } pu;
            pu.u4[0] = pk2bf(va.x, va.y);
            pu.u4[1] = pk2bf(va.z, va.w);
            pu.u4[2] = pk2bf(vb.x, vb.y);
            pu.u4[3] = pk2bf(vb.z, vb.w);
            const int cg = e * 2 + i;
            *(s16x8*)&dsP[r * 256 + ((cg ^ (r & 7)) << 3)] = pu.s;
        }
    }
    __syncthreads();
    // phase 1: logits = x2 @ read_w^T
    f32x4 acc[4] = {};
    for (int kt = 0; kt < 8; ++kt) {
        const int cg = kt * 4 + g;
        const s16x8 af = *(const s16x8*)&dsP[qi * 256 + ((cg ^ (qi & 7)) << 3)];
        #pragma unroll
        for (int nn = 0; nn < 4; ++nn) {
            const int wr = wn + nn * 16 + qi;
            const s16x8 bf = *(const s16x8*)&wRead[(size_t)wr * 256 + kt * 32 + g * 8];
            acc[nn] = __builtin_amdgcn_mfma_f32_16x16x32_bf16(af, bf, acc[nn], 0, 0, 0);
        }
    }
    // no-max softmax (logit std ~0.5)
    float p[4][4];
    float rs[4] = {0.f, 0.f, 0.f, 0.f};
    #pragma unroll
    for (int nn = 0; nn < 4; ++nn) {
        const float bb = read_b[wn + nn * 16 + qi];
        #pragma unroll
        for (int r = 0; r < 4; ++r) {
            p[nn][r] = __expf(acc[nn][r] + bb);
            rs[r] += p[nn][r];
        }
    }
    #pragma unroll
    for (int r = 0; r < 4; ++r) {
        rs[r] += __shfl_xor(rs[r], 1);
        rs[r] += __shfl_xor(rs[r], 2);
        rs[r] += __shfl_xor(rs[r], 4);
        rs[r] += __shfl_xor(rs[r], 8);
    }
    __syncthreads();   // all dsP (x2) reads done
    if (qi == 0) {
        #pragma unroll
        for (int r = 0; r < 4; ++r) lsum[wave][4 * g + r] = rs[r];
    }
    // write P over dsP (swizzled)
    #pragma unroll
    for (int nn = 0; nn < 4; ++nn) {
        #pragma unroll
        for (int r = 0; r < 4; ++r) {
            const int row = 4 * g + r, col = wn + nn * 16 + qi;
            const int cg = col >> 3, e = col & 7;
            dsP[row * 256 + ((cg ^ (row & 7)) << 3) + e] = f2bf(p[nn][r]);
        }
    }
    __syncthreads();
    if (tid < 16)
        lt[tid] = 1.f / (lsum[0][tid] + lsum[1][tid] + lsum[2][tid] + lsum[3][tid]);
    __syncthreads();
    // phase 2: O = P @ memT^T
    f32x4 acc2[4] = {};
    for (int kt = 0; kt < 8; ++kt) {
        const int cg = kt * 4 + g;
        const s16x8 af = *(const s16x8*)&dsP[qi * 256 + ((cg ^ (qi & 7)) << 3)];
        #pragma unroll
        for (int nn = 0; nn < 4; ++nn) {
            const int wr = wn + nn * 16 + qi;
            const s16x8 bf = *(const s16x8*)&wMemT[(size_t)wr * 256 + kt * 32 + g * 8];
            acc2[nn] = __builtin_amdgcn_mfma_f32_16x16x32_bf16(af, bf, acc2[nn], 0, 0, 0);
        }
    }
    // epilogue: x3 = O/l + x2 (in place) + fused LN3
    float xo[4][4];
    float s1[4] = {0.f, 0.f, 0.f, 0.f}, s2[4] = {0.f, 0.f, 0.f, 0.f};
    #pragma unroll
    for (int nn = 0; nn < 4; ++nn) {
        #pragma unroll
        for (int r = 0; r < 4; ++r) {
            const int row = 4 * g + r;
            const size_t idx = (size_t)(m0 + row) * 256 + wn + nn * 16 + qi;
            const float t = acc2[nn][r] * lt[row] + x2[idx];
            xout[idx] = t;
            xo[nn][r] = t;
            s1[r] += t; s2[r] += t * t;
        }
    }
    #pragma unroll
    for (int r = 0; r < 4; ++r) {
        s1[r] += __shfl_xor(s1[r], 1); s2[r] += __shfl_xor(s2[r], 1);
        s1[r] += __shfl_xor(s1[r], 2); s2[r] += __shfl_xor(s2[r], 2);
        s1[r] += __shfl_xor(s1[r], 4); s2[r] += __shfl_xor(s2[r], 4);
        s1[r] += __shfl_xor(s1[r], 8); s2[r] += __shfl_xor(s2[r], 8);
    }
    if (qi == 0) {
        #pragma unroll
        for (int r = 0; r < 4; ++r) { ws1[wave][4 * g + r] = s1[r]; ws2[wave][4 * g + r] = s2[r]; }
    }
    __syncthreads();
    #pragma unroll
    for (int r = 0; r < 4; ++r) {
        const int row = 4 * g + r;
        const float S1 = ws1[0][row] + ws1[1][row] + ws1[2][row] + ws1[3][row];
        const float S2 = ws2[0][row] + ws2[1][row] + ws2[2][row] + ws2[3][row];
        const float mean = S1 * (1.f / 256.f);
        const float rstd = rsqrtf(S2 * (1.f / 256.f) - mean * mean + kEps);
        #pragma unroll
        for (int nn = 0; nn < 4; ++nn) {
            const int col = wn + nn * 16 + qi;
            outln[(size_t)(m0 + row) * 256 + col] =
                f2bf((xo[nn][r] - mean) * rstd * lng[col] + lnb[col]);
        }
    }
}

// ---------- flash MFMA attention: kSP=5, QBLK=128, prefetched tr_read PV --
template <bool kAff>
__global__ __launch_bounds__(512) void attn_mfma_kernel(
        const ushort_t* __restrict__ q, const ushort_t* __restrict__ kbuf,
        const ushort_t* __restrict__ vbuf, ushort_t* __restrict__ o_part,
        float* __restrict__ l_part,
        const float* __restrict__ affinity, const int* __restrict__ did) {
    __shared__ ushort_t ldsK[SBLK * KPITCH];   // [s][d]  13824 B
    __shared__ ushort_t ldsV[SBLK * 16];       // [s][d]   9216 B
    const int tid  = threadIdx.x;
    const int bid  = blockIdx.x;
    const int w    = (bid & 7) * 220 + (bid >> 3);
    const int slice = w / 11;
    const int ttile = w - slice * 11;
    const int h    = slice & 15;
    const int z    = slice >> 4;
    const int b    = (z >= 5) ? 1 : 0;
    const int sp   = z - b * 5;
    const int t0   = ttile * 128;
    const int s0   = sp * kSLen;
    const int lane = tid & 63;
    const int wave = tid >> 6;
    const int g    = lane >> 4;
    const int qi   = lane & 15;

    const int tq  = t0 + wave * 16 + qi;
    const int tqc = min(tq, kT - 1);
    const ushort_t* qhb = q + (size_t)(b * 16 + h) * kT * 16;
    s16x8 qb = {0, 0, 0, 0, 0, 0, 0, 0};
    if (g < 2) qb = *(const s16x8*)&qhb[(size_t)tqc * 16 + g * 8];
    const float* ar = nullptr;
    if (kAff) ar = affinity + (size_t)did[b * kT + tqc] * kT;

    const ushort_t* kb  = kbuf + (size_t)(b * 16 + h) * kT * 16;
    const ushort_t* vbp = vbuf + (size_t)(b * 16 + h) * kT * 16;
    for (int i = tid; i < SBLK * 2; i += 512) {
        const int sl = i >> 1, hf = i & 1;
        const int sg = min(s0 + sl, kT - 1);
        *(s16x8*)&ldsK[sl * KPITCH + hf * 8] =
            *(const s16x8*)&kb[(size_t)sg * 16 + hf * 8];
        *(s16x8*)&ldsV[sl * 16 + hf * 8] =
            *(const s16x8*)&vbp[(size_t)sg * 16 + hf * 8];
    }
    __syncthreads();

    f32x4 acc = {0.f, 0.f, 0.f, 0.f};
    float lrun = 0.f;
    const unsigned vaddr = (unsigned)(size_t)(&ldsV[0]) + lane * 8;
    s16x4 va0, va1;
    asm volatile("ds_read_b64_tr_b16 %0, %2\n\t"
                 "ds_read_b64_tr_b16 %1, %2 offset:512"
                 : "=&v"(va0), "=&v"(va1) : "v"(vaddr));

    #pragma unroll
    for (int c = 0; c < SBLK / 32; ++c) {
        const int sl0 = c * 32;
        const bool tail = (c == 8);
        const s16x8 ka0 = *(const s16x8*)&ldsK[(sl0 + qi) * KPITCH + (g & 1) * 8];
        const s16x8 ka1 = *(const s16x8*)&ldsK[(sl0 + 16 + qi) * KPITCH + (g & 1) * 8];
        const f32x4 z4 = {0.f, 0.f, 0.f, 0.f};
        f32x4 d0 = __builtin_amdgcn_mfma_f32_16x16x32_bf16(ka0, qb, z4, 0, 0, 0);
        f32x4 d1 = __builtin_amdgcn_mfma_f32_16x16x32_bf16(ka1, qb, z4, 0, 0, 0);
        float sv[8];
        #pragma unroll
        for (int r = 0; r < 4; r++) { sv[r] = d0[r]; sv[4 + r] = d1[r]; }
        if (kAff) {
            if (!tail) {
                const float4 a0 = *(const float4*)&ar[s0 + sl0 + 4 * g];
                const float4 a1 = *(const float4*)&ar[s0 + sl0 + 16 + 4 * g];
                sv[0] += kAffScale * a0.x; sv[1] += kAffScale * a0.y;
                sv[2] += kAffScale * a0.z; sv[3] += kAffScale * a0.w;
                sv[4] += kAffScale * a1.x; sv[5] += kAffScale * a1.y;
                sv[6] += kAffScale * a1.z; sv[7] += kAffScale * a1.w;
            } else {
                #pragma unroll
                for (int jj = 0; jj < 8; jj++) {
                    const int s_ = s0 + sl0 + 16 * (jj >> 2) + 4 * g + (jj & 3);
                    sv[jj] += kAffScale * ar[min(s_, kT - 1)];
                }
            }
        }
        float pv[8];
        #pragma unroll
        for (int jj = 0; jj < 8; jj++) pv[jj] = fast_exp2(sv[jj]);
        if (tail && g >= 2) { pv[4] = 0.f; pv[5] = 0.f; pv[6] = 0.f; pv[7] = 0.f; }
        lrun += ((pv[0] + pv[1]) + (pv[2] + pv[3])) + ((pv[4] + pv[5]) + (pv[6] + pv[7]));
        union { unsigned u[4]; s16x8 s; } pu;
        pu.u[0] = pk2bf(pv[0], pv[1]);
        pu.u[1] = pk2bf(pv[2], pv[3]);
        pu.u[2] = pk2bf(pv[4], pv[5]);
        pu.u[3] = pk2bf(pv[6], pv[7]);
        asm volatile("s_waitcnt lgkmcnt(0)" ::: "memory");
        __builtin_amdgcn_sched_barrier(0);   // rule 18
        s16x8 af;
        #pragma unroll
        for (int j = 0; j < 4; j++) { af[j] = va0[j]; af[4 + j] = va1[j]; }
        acc = __builtin_amdgcn_mfma_f32_16x16x32_bf16(af, pu.s, acc, 0, 0, 0);
        if (c < SBLK / 32 - 1) {
            asm volatile("ds_read_b64_tr_b16 %0, %2\n\t"
                         "ds_read_b64_tr_b16 %1, %2 offset:512"
                         : "=&v"(va0), "=&v"(va1) : "v"(vaddr + (sl0 + 32) * 32));
        }
    }
    lrun += __shfl_xor(lrun, 16);
    lrun += __shfl_xor(lrun, 32);
    const int slice_id = (b * kSP + sp) * 16 + h;
    if (lane < 16 && tq < kT)
        l_part[(size_t)slice_id * kT + tq] = lrun;
    ushort_t* ob = o_part + (size_t)slice_id * kT * 16;
    s16x4 ov;
    #pragma unroll
    for (int r = 0; r < 4; r++) ov[r] = (short)f2bf(acc[r]);
    if (tq < kT) *(s16x4*)&ob[(size_t)tq * 16 + 4 * g] = ov;
}

}  // namespace

extern "C" void kernel_launch(void* const* d_in, const int* in_sizes, int n_in,
                              void* d_out, int out_size, void* d_ws, size_t ws_size,
                              hipStream_t stream) {
    const float* x          = (const float*)d_in[0];
    const int*   did        = (const int*)d_in[1];
    const float* in_proj_w  = (const float*)d_in[2];
    const float* in_proj_b  = (const float*)d_in[3];
    const float* out_proj_w = (const float*)d_in[4];
    const float* out_proj_b = (const float*)d_in[5];
    const float* ln1_g = (const float*)d_in[6];
    const float* ln1_b = (const float*)d_in[7];
    const float* ln2_g = (const float*)d_in[8];
    const float* ln2_b = (const float*)d_in[9];
    const float* ln3_g = (const float*)d_in[10];
    const float* ln3_b = (const float*)d_in[11];
    const float* gq_w = (const float*)d_in[12];
    const float* gq_b = (const float*)d_in[13];
    const float* gk_w = (const float*)d_in[14];
    const float* gk_b = (const float*)d_in[15];
    const float* gv_w = (const float*)d_in[16];
    const float* gv_b = (const float*)d_in[17];
    const float* go_w = (const float*)d_in[18];
    const float* go_b = (const float*)d_in[19];
    const float* affinity = (const float*)d_in[20];
    const float* mem_bank = (const float*)d_in[21];
    const float* read_w   = (const float*)d_in[22];
    const float* read_b   = (const float*)d_in[23];
    const float* ffn_w1 = (const float*)d_in[24];
    const float* ffn_b1 = (const float*)d_in[25];
    const float* ffn_w2 = (const float*)d_in[26];
    const float* ffn_b2 = (const float*)d_in[27];

    // ---- workspace layout (byte offsets; lifetimes hand-verified) ----
    char* wsb = (char*)d_ws;
    ushort_t* o_part  = (ushort_t*)(wsb + 0);          // [160][kT][16] bf16
    float*    l_part  = (float*)(wsb + 7168000);       // [160][kT] fp32
    ushort_t* ff116   = (ushort_t*)(wsb + 8064000);    // [BT,1024] (FFN phase)
    float*    bufD    = (float*)(wsb + 13798400);      // fp32 x2/x3
    ushort_t* bufA16  = (ushort_t*)(wsb + 16665600);   // bf16 LN out
    float*    bufD2   = (float*)(wsb + 18099200);      // fp32 x1
    ushort_t* bufQ16  = (ushort_t*)(wsb + 20966400);   // [B][H][T][16] (xQScale)
    ushort_t* bufK16  = (ushort_t*)(wsb + 22400000);   // [B][H][T][16]
    ushort_t* bufV16  = (ushort_t*)(wsb + 23833600);   // [B][H][T][16]
    ushort_t* wdst    = (ushort_t*)(wsb + 26700800);   // bf16 weights
    float*    gqkvb   = (float*)(wsb + 29191168);      // [768]

    const ushort_t* wQKV1 = wdst;
    const ushort_t* wG    = wdst + 196608;
    const ushort_t* wO    = wdst + 393216;
    const ushort_t* wGO   = wdst + 458752;
    const ushort_t* wF1   = wdst + 524288;
    const ushort_t* wF2   = wdst + 786432;
    const ushort_t* wRead = wdst + 1048576;
    const ushort_t* wMemT = wdst + 1114112;

    const dim3 blk(256);
    const int MT = (kBT + 63) / 64;        // 44
    const dim3 g_qkv(MT, 12), g_c(MT, 4), g_ff(MT, 16);
    const dim3 g_row(kBT / 16);            // 175
    const dim3 g_at(11 * kH * kB * kSP);   // 1760 = 8 * 220

    convert_kernel<<<609, blk, 0, stream>>>(in_proj_w, gq_w, gk_w, gv_w, out_proj_w,
                                            go_w, ffn_w1, ffn_w2, read_w, mem_bank,
                                            gq_b, gk_b, gv_b, wdst, gqkvb);
    // 1. h = LN1(x) -> bf16
    ln_kernel<<<kBT, blk, 0, stream>>>(x, ln1_g, ln1_b, bufA16);
    // 2. qkv = h @ in_proj^T + b -> head-major Q(xQScale)/K/V
    gemm16_kernel<<<g_qkv, blk, 0, stream>>>(bufA16, wQKV1, in_proj_b, nullptr,
                                             nullptr, bufQ16, bufK16, bufV16,
                                             kBT, 768, kC, 768, 0, 1);
    // 3. MHA partials
    attn_mfma_kernel<false><<<g_at, dim3(512), 0, stream>>>(bufQ16, bufK16, bufV16,
                                                            o_part, l_part,
                                                            nullptr, nullptr);
    // 4+5. x1 = x + combine(o) @ out_proj^T + b (fp32) + LN2(x1) bf16, fused
    gemmcomb_kernel<<<g_row, blk, 0, stream>>>(o_part, l_part, wO, out_proj_b,
                                               x, ln2_g, ln2_b, bufD2, bufA16);
    // 6. graph qkv (head-major split)
    gemm16_kernel<<<g_qkv, blk, 0, stream>>>(bufA16, wG, gqkvb, nullptr,
                                             nullptr, bufQ16, bufK16, bufV16,
                                             kBT, 768, kC, 768, 0, 1);
    // 7. graph attention partials
    attn_mfma_kernel<true><<<g_at, dim3(512), 0, stream>>>(bufQ16, bufK16, bufV16,
                                                           o_part, l_part,
                                                           affinity, did);
    // 8. x2 = x1 + combine(o2) @ go^T + b -> bufD fp32 (no LN)
    gemmcomb_kernel<<<g_row, blk, 0, stream>>>(o_part, l_part, wGO, go_b,
                                               bufD2, nullptr, nullptr,
                                               bufD, nullptr);
    // 9+10. x3 = x2 + softmax(x2@read_w^T+rb) @ mem_bank (in place) + LN3 fused
    memread_kernel<<<g_row, blk, 0, stream>>>(bufD, wRead, read_b, wMemT,
                                              ln3_g, ln3_b, bufD, bufA16);
    // 11. ff1 = gelu(LN3 @ w1^T + b1) -> bf16 [BT,1024]
    gemm16_kernel<<<g_ff, blk, 0, stream>>>(bufA16, wF1, ffn_b1, nullptr,
                                            nullptr, ff116, nullptr, nullptr,
                                            kBT, kFF, kC, kFF, 1, 0);
    // 12. out = x3 + ff1 @ w2^T + b2
    gemm16_kernel<<<g_c, blk, 0, stream>>>(ff116, wF2, ffn_b2, bufD,
                                           (float*)d_out, nullptr, nullptr, nullptr,
                                           kBT, kC, kFF, kC, 0, 0);
}